// Round 2
// baseline (12005.318 us; speedup 1.0000x reference)
//
#include <hip/hip_runtime.h>
#include <hip/hip_bf16.h>

// DGCNN forward on MI355X. Dtype-adaptive: a device probe detects whether the
// harness buffers are fp32 (reference dtypes) or bf16; everything is converted
// to fp32 in d_ws and computed in fp32. B=8, N=2048, K=20.

#define NEG_INF (-3.402823466e38f)
#define POS_INF (3.402823466e38f)

__device__ __forceinline__ float lk(float x) { return x > 0.f ? x : 0.2f * x; }

// ---------------- dtype probe: 1 = bf16, 0 = fp32 ----------------
__global__ void detect_dtype(const unsigned short* __restrict__ x16, int* __restrict__ flag) {
  if (threadIdx.x == 0 && blockIdx.x == 0) {
    int sane = 0;
    for (int i = 0; i < 64; ++i) {
      unsigned short u = x16[2 * i];   // low half of float i if fp32; element 2i if bf16
      int e = (u >> 7) & 0xff;
      if (e == 0 || (e >= 90 && e <= 140)) ++sane;
    }
    *flag = (sane >= 32) ? 1 : 0;
  }
}

// ---------------- batched convert-to-fp32 of all inputs ----------------
struct ConvTable {
  const void* src[30];
  float* dst[30];
  int n[30];
};

__global__ void conv_all(ConvTable t, const int* __restrict__ flag) {
  int e = blockIdx.y;
  int i = blockIdx.x * 256 + threadIdx.x;
  if (i >= t.n[e]) return;
  float v;
  if (*flag) v = __bfloat162float(((const __hip_bfloat16*)t.src[e])[i]);
  else       v = ((const float*)t.src[e])[i];
  t.dst[e][i] = v;
}

// ---------------- squared norms (accumulation order must match knn inner) ----
template <int C>
__global__ void sq_kernel(const float* __restrict__ xin, int ldx, float* __restrict__ sqb, int total) {
  int i = blockIdx.x * 256 + threadIdx.x;
  if (i >= total) return;
  const float* p = xin + (size_t)i * ldx;
  float s;
  if (C == 3) {
    s = 0.f;
    s = fmaf(p[0], p[0], s); s = fmaf(p[1], p[1], s); s = fmaf(p[2], p[2], s);
  } else {
    float4 a = make_float4(0.f, 0.f, 0.f, 0.f);
    for (int c = 0; c < C; c += 4) {
      float4 xv = *(const float4*)(p + c);
      a.x = fmaf(xv.x, xv.x, a.x); a.y = fmaf(xv.y, xv.y, a.y);
      a.z = fmaf(xv.z, xv.z, a.z); a.w = fmaf(xv.w, xv.w, a.w);
    }
    s = (a.x + a.y) + (a.z + a.w);
  }
  sqb[i] = s;
}

// ---------------- fused knn: distances + top-(K+1) selection ----------------
template <int C>
__global__ __launch_bounds__(256) void knn_kernel(
    const float* __restrict__ xin, int ldx, const float* __restrict__ sqb,
    int* __restrict__ idxout, int B, int N, int K) {
  constexpr int QB = 4;
  constexpr int CP = (C % 4 == 0) ? C : 4;
  __shared__ float dist[QB][2048];
  __shared__ float xq[QB][CP];
  __shared__ float rv[256];
  __shared__ int ri[256];
  const int tid = threadIdx.x;
  const int b = blockIdx.y;
  const int n0 = blockIdx.x * QB;

  for (int i = tid; i < QB * C; i += 256) {
    int q = i / C, c = i % C;
    xq[q][c] = xin[((size_t)(b * N) + n0 + q) * ldx + c];
  }
  __syncthreads();
  float sqq[QB];
#pragma unroll
  for (int q = 0; q < QB; ++q) sqq[q] = sqb[b * N + n0 + q];

  for (int m = tid; m < N; m += 256) {
    const float* xm = xin + ((size_t)(b * N) + m) * ldx;
    float inner[QB];
    if (C == 3) {
      float x0 = xm[0], x1 = xm[1], x2 = xm[2];
#pragma unroll
      for (int q = 0; q < QB; ++q) {
        float s = 0.f;
        s = fmaf(x0, xq[q][0], s); s = fmaf(x1, xq[q][1], s); s = fmaf(x2, xq[q][2], s);
        inner[q] = s;
      }
    } else {
      float4 acc[QB];
#pragma unroll
      for (int q = 0; q < QB; ++q) acc[q] = make_float4(0.f, 0.f, 0.f, 0.f);
      for (int c = 0; c < C; c += 4) {
        float4 xv = *(const float4*)(xm + c);
#pragma unroll
        for (int q = 0; q < QB; ++q) {
          acc[q].x = fmaf(xv.x, xq[q][c + 0], acc[q].x);
          acc[q].y = fmaf(xv.y, xq[q][c + 1], acc[q].y);
          acc[q].z = fmaf(xv.z, xq[q][c + 2], acc[q].z);
          acc[q].w = fmaf(xv.w, xq[q][c + 3], acc[q].w);
        }
      }
#pragma unroll
      for (int q = 0; q < QB; ++q)
        inner[q] = (acc[q].x + acc[q].y) + (acc[q].z + acc[q].w);
    }
    float sqm = sqb[b * N + m];
#pragma unroll
    for (int q = 0; q < QB; ++q) {
      float t = sqq[q] - 2.f * inner[q];
      t = t + sqm;
      dist[q][m] = -t;
    }
  }
  __syncthreads();

  for (int q = 0; q < QB; ++q) {
    for (int sel = 0; sel <= K; ++sel) {
      float bv = NEG_INF;
      int bi = N;
      for (int m = tid; m < N; m += 256) {
        float v = dist[q][m];
        if (v > bv || (v == bv && m < bi)) { bv = v; bi = m; }
      }
      rv[tid] = bv; ri[tid] = bi;
      __syncthreads();
      for (int off = 128; off > 0; off >>= 1) {
        if (tid < off) {
          float v2 = rv[tid + off]; int i2 = ri[tid + off];
          if (v2 > rv[tid] || (v2 == rv[tid] && i2 < ri[tid])) { rv[tid] = v2; ri[tid] = i2; }
        }
        __syncthreads();
      }
      if (tid == 0) {
        int w = ri[0];
        if (sel > 0) idxout[((size_t)(b * N) + n0 + q) * K + (sel - 1)] = w;
        if (w < 2048) dist[q][w] = NEG_INF;
      }
      __syncthreads();
    }
  }
}

// ---------------- build [W2 ; W1-W2] from edge weight (O, 2C), fp32 ---------
__global__ void wcomb_build(const float* __restrict__ w, float* __restrict__ wc, int O, int C) {
  int i = blockIdx.x * 256 + threadIdx.x;
  if (i >= O * C) return;
  int o = i / C, c = i % C;
  float w1 = w[o * 2 * C + c];
  float w2 = w[o * 2 * C + C + c];
  wc[(size_t)o * C + c] = w2;                 // u rows
  wc[(size_t)(O + o) * C + c] = w1 - w2;      // v rows
}

// ---------------- fp32 C = A(MxK,lda) * B(NcxK)^T ---------------------------
__global__ __launch_bounds__(256) void gemm_abt(
    const float* __restrict__ A, int lda, const float* __restrict__ Bm,
    float* __restrict__ Cm, int ldc, int M, int Nc, int K) {
  __shared__ float As[16][65];
  __shared__ float Bs[16][65];
  const int tid = threadIdx.x;
  const int tx = tid & 15, ty = tid >> 4;
  const int n0 = blockIdx.x * 64;
  const int m0 = blockIdx.y * 64;
  float acc[4][4] = {};
  const int nkt = (K + 15) / 16;
  for (int kt = 0; kt < nkt; ++kt) {
    int k0 = kt * 16;
#pragma unroll
    for (int ph = 0; ph < 4; ++ph) {
      int idx = tid + 256 * ph;
      int k = idx & 15, mr = idx >> 4;
      float v = 0.f;
      if (k0 + k < K) v = A[(size_t)(m0 + mr) * lda + k0 + k];
      As[k][mr] = v;
    }
#pragma unroll
    for (int ph = 0; ph < 4; ++ph) {
      int idx = tid + 256 * ph;
      int k = idx & 15, nr = idx >> 4;
      float v = 0.f;
      if (k0 + k < K) v = Bm[(size_t)(n0 + nr) * K + k0 + k];
      Bs[k][nr] = v;
    }
    __syncthreads();
#pragma unroll
    for (int kk = 0; kk < 16; ++kk) {
      float av[4], bv[4];
#pragma unroll
      for (int r = 0; r < 4; ++r) av[r] = As[kk][4 * ty + r];
#pragma unroll
      for (int c = 0; c < 4; ++c) bv[c] = Bs[kk][4 * tx + c];
#pragma unroll
      for (int r = 0; r < 4; ++r)
#pragma unroll
        for (int c = 0; c < 4; ++c) acc[r][c] = fmaf(av[r], bv[c], acc[r][c]);
    }
    __syncthreads();
  }
#pragma unroll
  for (int r = 0; r < 4; ++r) {
    float4 v = make_float4(acc[r][0], acc[r][1], acc[r][2], acc[r][3]);
    *(float4*)&Cm[(size_t)(m0 + 4 * ty + r) * ldc + n0 + 4 * tx] = v;
  }
}

// ---------------- edge conv pass1: h = v_n + u_m; stats + max/min over k ----
__global__ void edge_pass1(const float* __restrict__ uv, const int* __restrict__ idx,
                           float* __restrict__ hmax, float* __restrict__ hmin,
                           float* __restrict__ part, int N, int O, int K) {
  int b = blockIdx.y, n = blockIdx.x, o = threadIdx.x;
  size_t row = (size_t)b * N + n;
  const int twoO = 2 * O;
  float vv = uv[row * twoO + O + o];
  const int* ib = idx + row * K;
  float mx = NEG_INF, mn = POS_INF, s = 0.f, ss = 0.f;
  for (int k = 0; k < K; ++k) {
    int m = ib[k];
    float h = vv + uv[((size_t)b * N + m) * twoO + o];
    mx = fmaxf(mx, h); mn = fminf(mn, h);
    s += h; ss = fmaf(h, h, ss);
  }
  hmax[row * O + o] = mx;
  hmin[row * O + o] = mn;
  __shared__ float2 red[256];
  red[o] = make_float2(s, ss);
  __syncthreads();
  int gsz = O >> 2;
  int lane = o & (gsz - 1);
  for (int off = gsz >> 1; off > 0; off >>= 1) {
    if (lane < off) { red[o].x += red[o + off].x; red[o].y += red[o + off].y; }
    __syncthreads();
  }
  if (lane == 0) {
    int g = o / gsz;
    part[row * 8 + g * 2] = red[o].x;
    part[row * 8 + g * 2 + 1] = red[o].y;
  }
}

__global__ void stats_reduce(const float* __restrict__ part, float* __restrict__ st, int N) {
  int g = blockIdx.x, b = blockIdx.y, tid = threadIdx.x;
  float s = 0.f, ss = 0.f;
  for (int n = tid; n < N; n += 256) {
    size_t base = ((size_t)b * N + n) * 8 + g * 2;
    s += part[base]; ss += part[base + 1];
  }
  __shared__ float2 red[256];
  red[tid] = make_float2(s, ss);
  __syncthreads();
  for (int off = 128; off > 0; off >>= 1) {
    if (tid < off) { red[tid].x += red[tid + off].x; red[tid].y += red[tid + off].y; }
    __syncthreads();
  }
  if (tid == 0) { st[(b * 4 + g) * 2] = red[0].x; st[(b * 4 + g) * 2 + 1] = red[0].y; }
}

__global__ void edge_pass2(const float* __restrict__ hmax, const float* __restrict__ hmin,
                           const float* __restrict__ st,
                           const float* __restrict__ gw, const float* __restrict__ gb,
                           float* __restrict__ outbase, int N, int O, int K, int coloff, int total) {
  int i = blockIdx.x * 256 + threadIdx.x;
  if (i >= total) return;
  int o = i % O;
  int n = (i / O) % N;
  int b = i / (O * N);
  int gsz = O >> 2;
  int g = o / gsz;
  float S = st[(b * 4 + g) * 2], SS = st[(b * 4 + g) * 2 + 1];
  float cnt = (float)N * (float)K * (float)gsz;
  float mean = S / cnt;
  float var = SS / cnt - mean * mean;
  float rs = rsqrtf(var + 1e-5f);
  float wf = gw[o], bf = gb[o];
  float Mv = (wf >= 0.f) ? hmax[i] : hmin[i];
  float val = (Mv - mean) * rs * wf + bf;
  outbase[((size_t)b * N + n) * 512 + coloff + o] = lk(val);
}

// ---------------- gn_seq stats ----------------
__global__ void seq_stats(const float* __restrict__ h, float* __restrict__ st16,
                          float* __restrict__ maxv, float* __restrict__ minv, int N) {
  int b = blockIdx.y;
  int tid = threadIdx.x;
  int c = blockIdx.x * 256 + tid;
  float mx = NEG_INF, mn = POS_INF, s = 0.f, ss = 0.f;
  for (int n = 0; n < N; ++n) {
    float v = h[((size_t)b * N + n) * 1024 + c];
    mx = fmaxf(mx, v); mn = fminf(mn, v);
    s += v; ss = fmaf(v, v, ss);
  }
  maxv[b * 1024 + c] = mx;
  minv[b * 1024 + c] = mn;
  __shared__ float2 red[256];
  red[tid] = make_float2(s, ss);
  __syncthreads();
  int lane = tid & 63;
  for (int off = 32; off > 0; off >>= 1) {
    if (lane < off) { red[tid].x += red[tid + off].x; red[tid].y += red[tid + off].y; }
    __syncthreads();
  }
  if (lane == 0) {
    int g = c >> 6;
    st16[(b * 16 + g) * 2] = red[tid].x;
    st16[(b * 16 + g) * 2 + 1] = red[tid].y;
  }
}

__global__ void seq_apply(const float* __restrict__ st16, const float* __restrict__ maxv,
                          const float* __restrict__ minv, const float* __restrict__ gw,
                          const float* __restrict__ gb, float* __restrict__ g, int N) {
  int i = blockIdx.x * 256 + threadIdx.x;
  if (i >= 8 * 1024) return;
  int b = i >> 10, c = i & 1023;
  int grp = c >> 6;
  float S = st16[(b * 16 + grp) * 2], SS = st16[(b * 16 + grp) * 2 + 1];
  float cnt = (float)N * 64.f;
  float mean = S / cnt;
  float var = SS / cnt - mean * mean;
  float rs = rsqrtf(var + 1e-5f);
  float wf = gw[c], bf = gb[c];
  float Mv = (wf >= 0.f) ? maxv[i] : minv[i];
  g[i] = lk((Mv - mean) * rs * wf + bf);
}

// ---------------- small MLP head ----------------
__global__ void fc_kernel(const float* __restrict__ in, const float* __restrict__ w,
                          const float* __restrict__ bias, float* __restrict__ z,
                          int Cin, int Cout) {
  int b = blockIdx.y;
  int o = blockIdx.x * 64 + threadIdx.x;
  if (o >= Cout) return;
  const float* ir = in + (size_t)b * Cin;
  const float* wr = w + (size_t)o * Cin;
  float acc = 0.f;
  for (int c = 0; c < Cin; ++c) acc = fmaf(ir[c], wr[c], acc);
  z[b * Cout + o] = acc + bias[o];
}

__global__ void ln_leaky(const float* __restrict__ z, const float* __restrict__ w,
                         const float* __restrict__ bias, float* __restrict__ out, int Cn) {
  int b = blockIdx.x, tid = threadIdx.x;
  const float* zr = z + (size_t)b * Cn;
  float s = 0.f, ss = 0.f;
  for (int o = tid; o < Cn; o += 256) { float v = zr[o]; s += v; ss = fmaf(v, v, ss); }
  __shared__ float2 red[256];
  red[tid] = make_float2(s, ss);
  __syncthreads();
  for (int off = 128; off > 0; off >>= 1) {
    if (tid < off) { red[tid].x += red[tid + off].x; red[tid].y += red[tid + off].y; }
    __syncthreads();
  }
  float mean = red[0].x / Cn;
  float var = red[0].y / Cn - mean * mean;
  float rs = rsqrtf(var + 1e-5f);
  for (int o = tid; o < Cn; o += 256) {
    float v = (zr[o] - mean) * rs * w[o] + bias[o];
    out[b * Cn + o] = lk(v);
  }
}

__global__ void final_fc(const float* __restrict__ in, const float* __restrict__ w,
                         const float* __restrict__ bias, void* __restrict__ out,
                         const int* __restrict__ flag) {
  int t = threadIdx.x;
  if (t >= 16) return;
  int b = t >> 1, j = t & 1;
  float acc = 0.f;
  for (int c = 0; c < 64; ++c) acc = fmaf(in[b * 64 + c], w[j * 64 + c], acc);
  acc += bias[j];
  if (*flag) ((__hip_bfloat16*)out)[t] = __float2bfloat16(acc);
  else       ((float*)out)[t] = acc;
}

// ---------------- host-side dispatch helpers -----------------------
static void launch_sq(int C, const float* xin, int ldx, float* sqb, int BN, hipStream_t s) {
  dim3 g((BN + 255) / 256);
  if (C == 3)       sq_kernel<3><<<g, 256, 0, s>>>(xin, ldx, sqb, BN);
  else if (C == 64) sq_kernel<64><<<g, 256, 0, s>>>(xin, ldx, sqb, BN);
  else              sq_kernel<128><<<g, 256, 0, s>>>(xin, ldx, sqb, BN);
}
static void launch_knn(int C, const float* xin, int ldx, const float* sqb, int* idx,
                       int B, int N, int K, hipStream_t s) {
  dim3 g(N / 4, B);
  if (C == 3)       knn_kernel<3><<<g, 256, 0, s>>>(xin, ldx, sqb, idx, B, N, K);
  else if (C == 64) knn_kernel<64><<<g, 256, 0, s>>>(xin, ldx, sqb, idx, B, N, K);
  else              knn_kernel<128><<<g, 256, 0, s>>>(xin, ldx, sqb, idx, B, N, K);
}

extern "C" void kernel_launch(void* const* d_in, const int* in_sizes, int n_in,
                              void* d_out, int out_size, void* d_ws, size_t ws_size,
                              hipStream_t stream) {
  (void)out_size; (void)ws_size;
  const int B = 8, N = 2048, KNN = 20;
  const int BN = B * N;

  float* base = (float*)d_ws;
  size_t off = 0;
  auto alloc = [&](size_t nf) { float* p = base + off; off += nf; return p; };

  int*   FLAG  = (int*)alloc(16);
  float* XF    = alloc((size_t)BN * 3);
  float* HCAT  = alloc((size_t)BN * 512);
  float* BIG   = alloc((size_t)BN * 1024);   // UV | HMAX | HMIN during edge phase; H1024 after
  float* UV    = BIG;
  float* HMAX  = BIG + (size_t)BN * 512;
  float* HMIN  = BIG + (size_t)BN * 768;
  float* H1024 = BIG;
  float* SQB   = alloc(BN);
  float* WCOMB = alloc((size_t)512 * 128);
  float* PART  = alloc((size_t)BN * 8);
  float* ST4   = alloc(64);
  float* ST16  = alloc(512);
  float* MAXV  = alloc(8 * 1024);
  float* MINV  = alloc(8 * 1024);
  float* GVEC  = alloc(8 * 1024);
  float* Z1 = alloc(8 * 512); float* A1v = alloc(8 * 512);
  float* Z2 = alloc(8 * 256); float* A2v = alloc(8 * 256);
  float* Z3 = alloc(8 * 64);  float* A3v = alloc(8 * 64);
  int*   IDX = (int*)alloc((size_t)BN * KNN);

  // converted fp32 weights
  ConvTable ct;
  float* conv_dst[30];
  for (int i = 0; i < 30; ++i) {
    int n = in_sizes[i];
    conv_dst[i] = alloc((size_t)((n + 15) & ~15));
    ct.src[i] = d_in[i];
    ct.dst[i] = conv_dst[i];
    ct.n[i] = n;
  }
  ct.dst[0] = XF; ct.n[0] = BN * 3;   // x goes straight to XF

  const float* W_[4]  = {conv_dst[1], conv_dst[4], conv_dst[7], conv_dst[10]};
  const float* GW_[4] = {conv_dst[2], conv_dst[5], conv_dst[8], conv_dst[11]};
  const float* GB_[4] = {conv_dst[3], conv_dst[6], conv_dst[9], conv_dst[12]};
  const float* WM = conv_dst[13];
  const float* GMW = conv_dst[14], *GMB = conv_dst[15];
  const float* FC1W = conv_dst[16], *FC1B = conv_dst[17], *LN1W = conv_dst[18], *LN1B = conv_dst[19];
  const float* FC2W = conv_dst[20], *FC2B = conv_dst[21], *LN2W = conv_dst[22], *LN2B = conv_dst[23];
  const float* FC3W = conv_dst[24], *FC3B = conv_dst[25], *LN3W = conv_dst[26], *LN3B = conv_dst[27];
  const float* FC4W = conv_dst[28], *FC4B = conv_dst[29];

  detect_dtype<<<dim3(1), 64, 0, stream>>>((const unsigned short*)d_in[0], FLAG);
  conv_all<<<dim3(2048, 30), 256, 0, stream>>>(ct, FLAG);

  const int Cs[4]     = {3, 64, 64, 128};
  const int Os[4]     = {64, 64, 128, 256};
  const int incol[4]  = {0, 0, 64, 128};
  const int outcol[4] = {0, 64, 128, 256};

  for (int l = 0; l < 4; ++l) {
    const int C = Cs[l], O = Os[l], twoO = 2 * O;
    const float* xin = (l == 0) ? XF : (HCAT + incol[l]);
    const int ldx = (l == 0) ? 3 : 512;

    launch_sq(C, xin, ldx, SQB, BN, stream);
    launch_knn(C, xin, ldx, SQB, IDX, B, N, KNN, stream);
    wcomb_build<<<dim3((O * C + 255) / 256), 256, 0, stream>>>(W_[l], WCOMB, O, C);
    gemm_abt<<<dim3(twoO / 64, BN / 64), 256, 0, stream>>>(xin, ldx, WCOMB, UV, twoO, BN, twoO, C);
    edge_pass1<<<dim3(N, B), O, 0, stream>>>(UV, IDX, HMAX, HMIN, PART, N, O, KNN);
    stats_reduce<<<dim3(4, B), 256, 0, stream>>>(PART, ST4, N);
    int tot = BN * O;
    edge_pass2<<<dim3((tot + 255) / 256), 256, 0, stream>>>(HMAX, HMIN, ST4, GW_[l], GB_[l],
                                                            HCAT, N, O, KNN, outcol[l], tot);
  }

  gemm_abt<<<dim3(1024 / 64, BN / 64), 256, 0, stream>>>(HCAT, 512, WM, H1024, 1024, BN, 1024, 512);
  seq_stats<<<dim3(4, B), 256, 0, stream>>>(H1024, ST16, MAXV, MINV, N);
  seq_apply<<<dim3(32), 256, 0, stream>>>(ST16, MAXV, MINV, GMW, GMB, GVEC, N);

  fc_kernel<<<dim3(8, 8), 64, 0, stream>>>(GVEC, FC1W, FC1B, Z1, 1024, 512);
  ln_leaky<<<dim3(8), 256, 0, stream>>>(Z1, LN1W, LN1B, A1v, 512);
  fc_kernel<<<dim3(4, 8), 64, 0, stream>>>(A1v, FC2W, FC2B, Z2, 512, 256);
  ln_leaky<<<dim3(8), 256, 0, stream>>>(Z2, LN2W, LN2B, A2v, 256);
  fc_kernel<<<dim3(1, 8), 64, 0, stream>>>(A2v, FC3W, FC3B, Z3, 256, 64);
  ln_leaky<<<dim3(8), 256, 0, stream>>>(Z3, LN3W, LN3B, A3v, 64);
  final_fc<<<dim3(1), 64, 0, stream>>>(A3v, FC4W, FC4B, d_out, FLAG);
}

// Round 3
// 5299.340 us; speedup vs baseline: 2.2654x; 2.2654x over previous
//
#include <hip/hip_runtime.h>
#include <hip/hip_bf16.h>

// DGCNN forward on MI355X. Dtype-adaptive: a device probe detects whether the
// harness buffers are fp32 (reference dtypes) or bf16; everything is converted
// to fp32 in d_ws and computed in fp32. B=8, N=2048, K=20.

#define NEG_INF (-3.402823466e38f)
#define POS_INF (3.402823466e38f)

__device__ __forceinline__ float lk(float x) { return x > 0.f ? x : 0.2f * x; }

// ---------------- dtype probe: 1 = bf16, 0 = fp32 ----------------
__global__ void detect_dtype(const unsigned short* __restrict__ x16, int* __restrict__ flag) {
  if (threadIdx.x == 0 && blockIdx.x == 0) {
    int sane = 0;
    for (int i = 0; i < 64; ++i) {
      unsigned short u = x16[2 * i];   // low half of float i if fp32; element 2i if bf16
      int e = (u >> 7) & 0xff;
      if (e == 0 || (e >= 90 && e <= 140)) ++sane;
    }
    *flag = (sane >= 32) ? 1 : 0;
  }
}

// ---------------- batched convert-to-fp32 of all inputs ----------------
struct ConvTable {
  const void* src[30];
  float* dst[30];
  int n[30];
};

__global__ void conv_all(ConvTable t, const int* __restrict__ flag) {
  int e = blockIdx.y;
  int i = blockIdx.x * 256 + threadIdx.x;
  if (i >= t.n[e]) return;
  float v;
  if (*flag) v = __bfloat162float(((const __hip_bfloat16*)t.src[e])[i]);
  else       v = ((const float*)t.src[e])[i];
  t.dst[e][i] = v;
}

// ---------------- squared norms (accumulation order must match knn inner) ----
template <int C>
__global__ void sq_kernel(const float* __restrict__ xin, int ldx, float* __restrict__ sqb, int total) {
  int i = blockIdx.x * 256 + threadIdx.x;
  if (i >= total) return;
  const float* p = xin + (size_t)i * ldx;
  float s;
  if (C == 3) {
    s = 0.f;
    s = fmaf(p[0], p[0], s); s = fmaf(p[1], p[1], s); s = fmaf(p[2], p[2], s);
  } else {
    float4 a = make_float4(0.f, 0.f, 0.f, 0.f);
    for (int c = 0; c < C; c += 4) {
      float4 xv = *(const float4*)(p + c);
      a.x = fmaf(xv.x, xv.x, a.x); a.y = fmaf(xv.y, xv.y, a.y);
      a.z = fmaf(xv.z, xv.z, a.z); a.w = fmaf(xv.w, xv.w, a.w);
    }
    s = (a.x + a.y) + (a.z + a.w);
  }
  sqb[i] = s;
}

// ---------------- fused knn: distances + wave-level top-(K+1) ----------------
// Block = 256 threads = 4 waves, QB=4 queries. Distance phase: 256 threads
// strided over m (unchanged). Selection: wave w owns query w; lane-local
// argmax over 32 strided columns + 6-step shuffle butterfly per extraction,
// winner lane invalidates + rescans. ONE __syncthreads total.
template <int C>
__global__ __launch_bounds__(256) void knn_kernel(
    const float* __restrict__ xin, int ldx, const float* __restrict__ sqb,
    int* __restrict__ idxout, int B, int N, int K) {
  constexpr int QB = 4;
  constexpr int CP = (C % 4 == 0) ? C : 4;
  __shared__ float dist[QB][2048];
  __shared__ float xq[QB][CP];
  const int tid = threadIdx.x;
  const int lane = tid & 63;
  const int wave = tid >> 6;
  const int b = blockIdx.y;
  const int n0 = blockIdx.x * QB;

  for (int i = tid; i < QB * C; i += 256) {
    int q = i / C, c = i % C;
    xq[q][c] = xin[((size_t)(b * N) + n0 + q) * ldx + c];
  }
  __syncthreads();
  float sqq[QB];
#pragma unroll
  for (int q = 0; q < QB; ++q) sqq[q] = sqb[b * N + n0 + q];

  for (int m = tid; m < N; m += 256) {
    const float* xm = xin + ((size_t)(b * N) + m) * ldx;
    float inner[QB];
    if (C == 3) {
      float x0 = xm[0], x1 = xm[1], x2 = xm[2];
#pragma unroll
      for (int q = 0; q < QB; ++q) {
        float s = 0.f;
        s = fmaf(x0, xq[q][0], s); s = fmaf(x1, xq[q][1], s); s = fmaf(x2, xq[q][2], s);
        inner[q] = s;
      }
    } else {
      float4 acc[QB];
#pragma unroll
      for (int q = 0; q < QB; ++q) acc[q] = make_float4(0.f, 0.f, 0.f, 0.f);
      for (int c = 0; c < C; c += 4) {
        float4 xv = *(const float4*)(xm + c);
#pragma unroll
        for (int q = 0; q < QB; ++q) {
          acc[q].x = fmaf(xv.x, xq[q][c + 0], acc[q].x);
          acc[q].y = fmaf(xv.y, xq[q][c + 1], acc[q].y);
          acc[q].z = fmaf(xv.z, xq[q][c + 2], acc[q].z);
          acc[q].w = fmaf(xv.w, xq[q][c + 3], acc[q].w);
        }
      }
#pragma unroll
      for (int q = 0; q < QB; ++q)
        inner[q] = (acc[q].x + acc[q].y) + (acc[q].z + acc[q].w);
    }
    float sqm = sqb[b * N + m];
#pragma unroll
    for (int q = 0; q < QB; ++q) {
      float t = sqq[q] - 2.f * inner[q];
      t = t + sqm;
      dist[q][m] = -t;
    }
  }
  __syncthreads();

  // ---- wave-level selection: wave owns query q = wave ----
  {
    const int q = wave;
    const int nq = n0 + q;
    float lv = NEG_INF;
    int lm = 0;
    for (int i = 0; i < 32; ++i) {
      int m = 64 * i + lane;
      float v = dist[q][m];
      if (v > lv) { lv = v; lm = m; }   // ascending m: strict > keeps min index
    }
    for (int sel = 0; sel <= K; ++sel) {
      float bv = lv;
      int bm = lm;
#pragma unroll
      for (int s = 1; s < 64; s <<= 1) {
        float ov = __shfl_xor(bv, s);
        int om = __shfl_xor(bm, s);
        if (ov > bv || (ov == bv && om < bm)) { bv = ov; bm = om; }
      }
      if (sel > 0 && lane == 0)
        idxout[((size_t)(b * N) + nq) * K + (sel - 1)] = bm;
      if ((bm & 63) == lane) {
        dist[q][bm] = NEG_INF;
        lv = NEG_INF; lm = 0;
        for (int i = 0; i < 32; ++i) {
          int m = 64 * i + lane;
          float v = dist[q][m];
          if (v > lv) { lv = v; lm = m; }
        }
      }
    }
  }
}

// ---------------- build [W2 ; W1-W2] from edge weight (O, 2C), fp32 ---------
__global__ void wcomb_build(const float* __restrict__ w, float* __restrict__ wc, int O, int C) {
  int i = blockIdx.x * 256 + threadIdx.x;
  if (i >= O * C) return;
  int o = i / C, c = i % C;
  float w1 = w[o * 2 * C + c];
  float w2 = w[o * 2 * C + C + c];
  wc[(size_t)o * C + c] = w2;                 // u rows
  wc[(size_t)(O + o) * C + c] = w1 - w2;      // v rows
}

// ---------------- fp32 C = A(MxK,lda) * B(NcxK)^T ---------------------------
__global__ __launch_bounds__(256) void gemm_abt(
    const float* __restrict__ A, int lda, const float* __restrict__ Bm,
    float* __restrict__ Cm, int ldc, int M, int Nc, int K) {
  __shared__ float As[16][65];
  __shared__ float Bs[16][65];
  const int tid = threadIdx.x;
  const int tx = tid & 15, ty = tid >> 4;
  const int n0 = blockIdx.x * 64;
  const int m0 = blockIdx.y * 64;
  float acc[4][4] = {};
  const int nkt = (K + 15) / 16;
  for (int kt = 0; kt < nkt; ++kt) {
    int k0 = kt * 16;
#pragma unroll
    for (int ph = 0; ph < 4; ++ph) {
      int idx = tid + 256 * ph;
      int k = idx & 15, mr = idx >> 4;
      float v = 0.f;
      if (k0 + k < K) v = A[(size_t)(m0 + mr) * lda + k0 + k];
      As[k][mr] = v;
    }
#pragma unroll
    for (int ph = 0; ph < 4; ++ph) {
      int idx = tid + 256 * ph;
      int k = idx & 15, nr = idx >> 4;
      float v = 0.f;
      if (k0 + k < K) v = Bm[(size_t)(n0 + nr) * K + k0 + k];
      Bs[k][nr] = v;
    }
    __syncthreads();
#pragma unroll
    for (int kk = 0; kk < 16; ++kk) {
      float av[4], bv[4];
#pragma unroll
      for (int r = 0; r < 4; ++r) av[r] = As[kk][4 * ty + r];
#pragma unroll
      for (int c = 0; c < 4; ++c) bv[c] = Bs[kk][4 * tx + c];
#pragma unroll
      for (int r = 0; r < 4; ++r)
#pragma unroll
        for (int c = 0; c < 4; ++c) acc[r][c] = fmaf(av[r], bv[c], acc[r][c]);
    }
    __syncthreads();
  }
#pragma unroll
  for (int r = 0; r < 4; ++r) {
    float4 v = make_float4(acc[r][0], acc[r][1], acc[r][2], acc[r][3]);
    *(float4*)&Cm[(size_t)(m0 + 4 * ty + r) * ldc + n0 + 4 * tx] = v;
  }
}

// ---------------- edge conv pass1: h = v_n + u_m; stats + max/min over k ----
__global__ void edge_pass1(const float* __restrict__ uv, const int* __restrict__ idx,
                           float* __restrict__ hmax, float* __restrict__ hmin,
                           float* __restrict__ part, int N, int O, int K) {
  int b = blockIdx.y, n = blockIdx.x, o = threadIdx.x;
  size_t row = (size_t)b * N + n;
  const int twoO = 2 * O;
  float vv = uv[row * twoO + O + o];
  const int* ib = idx + row * K;
  float mx = NEG_INF, mn = POS_INF, s = 0.f, ss = 0.f;
  for (int k = 0; k < K; ++k) {
    int m = ib[k];
    float h = vv + uv[((size_t)b * N + m) * twoO + o];
    mx = fmaxf(mx, h); mn = fminf(mn, h);
    s += h; ss = fmaf(h, h, ss);
  }
  hmax[row * O + o] = mx;
  hmin[row * O + o] = mn;
  __shared__ float2 red[256];
  red[o] = make_float2(s, ss);
  __syncthreads();
  int gsz = O >> 2;
  int lane = o & (gsz - 1);
  for (int off = gsz >> 1; off > 0; off >>= 1) {
    if (lane < off) { red[o].x += red[o + off].x; red[o].y += red[o + off].y; }
    __syncthreads();
  }
  if (lane == 0) {
    int g = o / gsz;
    part[row * 8 + g * 2] = red[o].x;
    part[row * 8 + g * 2 + 1] = red[o].y;
  }
}

__global__ void stats_reduce(const float* __restrict__ part, float* __restrict__ st, int N) {
  int g = blockIdx.x, b = blockIdx.y, tid = threadIdx.x;
  float s = 0.f, ss = 0.f;
  for (int n = tid; n < N; n += 256) {
    size_t base = ((size_t)b * N + n) * 8 + g * 2;
    s += part[base]; ss += part[base + 1];
  }
  __shared__ float2 red[256];
  red[tid] = make_float2(s, ss);
  __syncthreads();
  for (int off = 128; off > 0; off >>= 1) {
    if (tid < off) { red[tid].x += red[tid + off].x; red[tid].y += red[tid + off].y; }
    __syncthreads();
  }
  if (tid == 0) { st[(b * 4 + g) * 2] = red[0].x; st[(b * 4 + g) * 2 + 1] = red[0].y; }
}

__global__ void edge_pass2(const float* __restrict__ hmax, const float* __restrict__ hmin,
                           const float* __restrict__ st,
                           const float* __restrict__ gw, const float* __restrict__ gb,
                           float* __restrict__ outbase, int N, int O, int K, int coloff, int total) {
  int i = blockIdx.x * 256 + threadIdx.x;
  if (i >= total) return;
  int o = i % O;
  int n = (i / O) % N;
  int b = i / (O * N);
  int gsz = O >> 2;
  int g = o / gsz;
  float S = st[(b * 4 + g) * 2], SS = st[(b * 4 + g) * 2 + 1];
  float cnt = (float)N * (float)K * (float)gsz;
  float mean = S / cnt;
  float var = SS / cnt - mean * mean;
  float rs = rsqrtf(var + 1e-5f);
  float wf = gw[o], bf = gb[o];
  float Mv = (wf >= 0.f) ? hmax[i] : hmin[i];
  float val = (Mv - mean) * rs * wf + bf;
  outbase[((size_t)b * N + n) * 512 + coloff + o] = lk(val);
}

// ---------------- gn_seq stats ----------------
__global__ void seq_stats(const float* __restrict__ h, float* __restrict__ st16,
                          float* __restrict__ maxv, float* __restrict__ minv, int N) {
  int b = blockIdx.y;
  int tid = threadIdx.x;
  int c = blockIdx.x * 256 + tid;
  float mx = NEG_INF, mn = POS_INF, s = 0.f, ss = 0.f;
  for (int n = 0; n < N; ++n) {
    float v = h[((size_t)b * N + n) * 1024 + c];
    mx = fmaxf(mx, v); mn = fminf(mn, v);
    s += v; ss = fmaf(v, v, ss);
  }
  maxv[b * 1024 + c] = mx;
  minv[b * 1024 + c] = mn;
  __shared__ float2 red[256];
  red[tid] = make_float2(s, ss);
  __syncthreads();
  int lane = tid & 63;
  for (int off = 32; off > 0; off >>= 1) {
    if (lane < off) { red[tid].x += red[tid + off].x; red[tid].y += red[tid + off].y; }
    __syncthreads();
  }
  if (lane == 0) {
    int g = c >> 6;
    st16[(b * 16 + g) * 2] = red[tid].x;
    st16[(b * 16 + g) * 2 + 1] = red[tid].y;
  }
}

__global__ void seq_apply(const float* __restrict__ st16, const float* __restrict__ maxv,
                          const float* __restrict__ minv, const float* __restrict__ gw,
                          const float* __restrict__ gb, float* __restrict__ g, int N) {
  int i = blockIdx.x * 256 + threadIdx.x;
  if (i >= 8 * 1024) return;
  int b = i >> 10, c = i & 1023;
  int grp = c >> 6;
  float S = st16[(b * 16 + grp) * 2], SS = st16[(b * 16 + grp) * 2 + 1];
  float cnt = (float)N * 64.f;
  float mean = S / cnt;
  float var = SS / cnt - mean * mean;
  float rs = rsqrtf(var + 1e-5f);
  float wf = gw[c], bf = gb[c];
  float Mv = (wf >= 0.f) ? maxv[i] : minv[i];
  g[i] = lk((Mv - mean) * rs * wf + bf);
}

// ---------------- small MLP head ----------------
__global__ void fc_kernel(const float* __restrict__ in, const float* __restrict__ w,
                          const float* __restrict__ bias, float* __restrict__ z,
                          int Cin, int Cout) {
  int b = blockIdx.y;
  int o = blockIdx.x * 64 + threadIdx.x;
  if (o >= Cout) return;
  const float* ir = in + (size_t)b * Cin;
  const float* wr = w + (size_t)o * Cin;
  float acc = 0.f;
  for (int c = 0; c < Cin; ++c) acc = fmaf(ir[c], wr[c], acc);
  z[b * Cout + o] = acc + bias[o];
}

__global__ void ln_leaky(const float* __restrict__ z, const float* __restrict__ w,
                         const float* __restrict__ bias, float* __restrict__ out, int Cn) {
  int b = blockIdx.x, tid = threadIdx.x;
  const float* zr = z + (size_t)b * Cn;
  float s = 0.f, ss = 0.f;
  for (int o = tid; o < Cn; o += 256) { float v = zr[o]; s += v; ss = fmaf(v, v, ss); }
  __shared__ float2 red[256];
  red[tid] = make_float2(s, ss);
  __syncthreads();
  for (int off = 128; off > 0; off >>= 1) {
    if (tid < off) { red[tid].x += red[tid + off].x; red[tid].y += red[tid + off].y; }
    __syncthreads();
  }
  float mean = red[0].x / Cn;
  float var = red[0].y / Cn - mean * mean;
  float rs = rsqrtf(var + 1e-5f);
  for (int o = tid; o < Cn; o += 256) {
    float v = (zr[o] - mean) * rs * w[o] + bias[o];
    out[b * Cn + o] = lk(v);
  }
}

__global__ void final_fc(const float* __restrict__ in, const float* __restrict__ w,
                         const float* __restrict__ bias, void* __restrict__ out,
                         const int* __restrict__ flag) {
  int t = threadIdx.x;
  if (t >= 16) return;
  int b = t >> 1, j = t & 1;
  float acc = 0.f;
  for (int c = 0; c < 64; ++c) acc = fmaf(in[b * 64 + c], w[j * 64 + c], acc);
  acc += bias[j];
  if (*flag) ((__hip_bfloat16*)out)[t] = __float2bfloat16(acc);
  else       ((float*)out)[t] = acc;
}

// ---------------- host-side dispatch helpers -----------------------
static void launch_sq(int C, const float* xin, int ldx, float* sqb, int BN, hipStream_t s) {
  dim3 g((BN + 255) / 256);
  if (C == 3)       sq_kernel<3><<<g, 256, 0, s>>>(xin, ldx, sqb, BN);
  else if (C == 64) sq_kernel<64><<<g, 256, 0, s>>>(xin, ldx, sqb, BN);
  else              sq_kernel<128><<<g, 256, 0, s>>>(xin, ldx, sqb, BN);
}
static void launch_knn(int C, const float* xin, int ldx, const float* sqb, int* idx,
                       int B, int N, int K, hipStream_t s) {
  dim3 g(N / 4, B);
  if (C == 3)       knn_kernel<3><<<g, 256, 0, s>>>(xin, ldx, sqb, idx, B, N, K);
  else if (C == 64) knn_kernel<64><<<g, 256, 0, s>>>(xin, ldx, sqb, idx, B, N, K);
  else              knn_kernel<128><<<g, 256, 0, s>>>(xin, ldx, sqb, idx, B, N, K);
}

extern "C" void kernel_launch(void* const* d_in, const int* in_sizes, int n_in,
                              void* d_out, int out_size, void* d_ws, size_t ws_size,
                              hipStream_t stream) {
  (void)out_size; (void)ws_size;
  const int B = 8, N = 2048, KNN = 20;
  const int BN = B * N;

  float* base = (float*)d_ws;
  size_t off = 0;
  auto alloc = [&](size_t nf) { float* p = base + off; off += nf; return p; };

  int*   FLAG  = (int*)alloc(16);
  float* XF    = alloc((size_t)BN * 3);
  float* HCAT  = alloc((size_t)BN * 512);
  float* BIG   = alloc((size_t)BN * 1024);   // UV | HMAX | HMIN during edge phase; H1024 after
  float* UV    = BIG;
  float* HMAX  = BIG + (size_t)BN * 512;
  float* HMIN  = BIG + (size_t)BN * 768;
  float* H1024 = BIG;
  float* SQB   = alloc(BN);
  float* WCOMB = alloc((size_t)512 * 128);
  float* PART  = alloc((size_t)BN * 8);
  float* ST4   = alloc(64);
  float* ST16  = alloc(512);
  float* MAXV  = alloc(8 * 1024);
  float* MINV  = alloc(8 * 1024);
  float* GVEC  = alloc(8 * 1024);
  float* Z1 = alloc(8 * 512); float* A1v = alloc(8 * 512);
  float* Z2 = alloc(8 * 256); float* A2v = alloc(8 * 256);
  float* Z3 = alloc(8 * 64);  float* A3v = alloc(8 * 64);
  int*   IDX = (int*)alloc((size_t)BN * KNN);

  // converted fp32 weights
  ConvTable ct;
  float* conv_dst[30];
  for (int i = 0; i < 30; ++i) {
    int n = in_sizes[i];
    conv_dst[i] = alloc((size_t)((n + 15) & ~15));
    ct.src[i] = d_in[i];
    ct.dst[i] = conv_dst[i];
    ct.n[i] = n;
  }
  ct.dst[0] = XF; ct.n[0] = BN * 3;   // x goes straight to XF

  const float* W_[4]  = {conv_dst[1], conv_dst[4], conv_dst[7], conv_dst[10]};
  const float* GW_[4] = {conv_dst[2], conv_dst[5], conv_dst[8], conv_dst[11]};
  const float* GB_[4] = {conv_dst[3], conv_dst[6], conv_dst[9], conv_dst[12]};
  const float* WM = conv_dst[13];
  const float* GMW = conv_dst[14], *GMB = conv_dst[15];
  const float* FC1W = conv_dst[16], *FC1B = conv_dst[17], *LN1W = conv_dst[18], *LN1B = conv_dst[19];
  const float* FC2W = conv_dst[20], *FC2B = conv_dst[21], *LN2W = conv_dst[22], *LN2B = conv_dst[23];
  const float* FC3W = conv_dst[24], *FC3B = conv_dst[25], *LN3W = conv_dst[26], *LN3B = conv_dst[27];
  const float* FC4W = conv_dst[28], *FC4B = conv_dst[29];

  detect_dtype<<<dim3(1), 64, 0, stream>>>((const unsigned short*)d_in[0], FLAG);
  conv_all<<<dim3(2048, 30), 256, 0, stream>>>(ct, FLAG);

  const int Cs[4]     = {3, 64, 64, 128};
  const int Os[4]     = {64, 64, 128, 256};
  const int incol[4]  = {0, 0, 64, 128};
  const int outcol[4] = {0, 64, 128, 256};

  for (int l = 0; l < 4; ++l) {
    const int C = Cs[l], O = Os[l], twoO = 2 * O;
    const float* xin = (l == 0) ? XF : (HCAT + incol[l]);
    const int ldx = (l == 0) ? 3 : 512;

    launch_sq(C, xin, ldx, SQB, BN, stream);
    launch_knn(C, xin, ldx, SQB, IDX, B, N, KNN, stream);
    wcomb_build<<<dim3((O * C + 255) / 256), 256, 0, stream>>>(W_[l], WCOMB, O, C);
    gemm_abt<<<dim3(twoO / 64, BN / 64), 256, 0, stream>>>(xin, ldx, WCOMB, UV, twoO, BN, twoO, C);
    edge_pass1<<<dim3(N, B), O, 0, stream>>>(UV, IDX, HMAX, HMIN, PART, N, O, KNN);
    stats_reduce<<<dim3(4, B), 256, 0, stream>>>(PART, ST4, N);
    int tot = BN * O;
    edge_pass2<<<dim3((tot + 255) / 256), 256, 0, stream>>>(HMAX, HMIN, ST4, GW_[l], GB_[l],
                                                            HCAT, N, O, KNN, outcol[l], tot);
  }

  gemm_abt<<<dim3(1024 / 64, BN / 64), 256, 0, stream>>>(HCAT, 512, WM, H1024, 1024, BN, 1024, 512);
  seq_stats<<<dim3(4, B), 256, 0, stream>>>(H1024, ST16, MAXV, MINV, N);
  seq_apply<<<dim3(32), 256, 0, stream>>>(ST16, MAXV, MINV, GMW, GMB, GVEC, N);

  fc_kernel<<<dim3(8, 8), 64, 0, stream>>>(GVEC, FC1W, FC1B, Z1, 1024, 512);
  ln_leaky<<<dim3(8), 256, 0, stream>>>(Z1, LN1W, LN1B, A1v, 512);
  fc_kernel<<<dim3(4, 8), 64, 0, stream>>>(A1v, FC2W, FC2B, Z2, 512, 256);
  ln_leaky<<<dim3(8), 256, 0, stream>>>(Z2, LN2W, LN2B, A2v, 256);
  fc_kernel<<<dim3(1, 8), 64, 0, stream>>>(A2v, FC3W, FC3B, Z3, 256, 64);
  ln_leaky<<<dim3(8), 256, 0, stream>>>(Z3, LN3W, LN3B, A3v, 64);
  final_fc<<<dim3(1), 64, 0, stream>>>(A3v, FC4W, FC4B, d_out, FLAG);
}

// Round 4
// 2948.757 us; speedup vs baseline: 4.0713x; 1.7971x over previous
//
#include <hip/hip_runtime.h>
#include <hip/hip_bf16.h>

// DGCNN forward on MI355X. Dtype-adaptive: a device probe detects whether the
// harness buffers are fp32 (reference dtypes) or bf16; everything is converted
// to fp32 in d_ws and computed in fp32. B=8, N=2048, K=20.

#define NEG_INF (-3.402823466e38f)
#define POS_INF (3.402823466e38f)

__device__ __forceinline__ float lk(float x) { return x > 0.f ? x : 0.2f * x; }

// ---------------- dtype probe: 1 = bf16, 0 = fp32 ----------------
__global__ void detect_dtype(const unsigned short* __restrict__ x16, int* __restrict__ flag) {
  if (threadIdx.x == 0 && blockIdx.x == 0) {
    int sane = 0;
    for (int i = 0; i < 64; ++i) {
      unsigned short u = x16[2 * i];   // low half of float i if fp32; element 2i if bf16
      int e = (u >> 7) & 0xff;
      if (e == 0 || (e >= 90 && e <= 140)) ++sane;
    }
    *flag = (sane >= 32) ? 1 : 0;
  }
}

// ---------------- batched convert-to-fp32 of all inputs ----------------
struct ConvTable {
  const void* src[30];
  float* dst[30];
  int n[30];
};

__global__ void conv_all(ConvTable t, const int* __restrict__ flag) {
  int e = blockIdx.y;
  int i = blockIdx.x * 256 + threadIdx.x;
  if (i >= t.n[e]) return;
  float v;
  if (*flag) v = __bfloat162float(((const __hip_bfloat16*)t.src[e])[i]);
  else       v = ((const float*)t.src[e])[i];
  t.dst[e][i] = v;
}

// ---------------- squared norms (accumulation order must match knn inner) ----
template <int C>
__global__ void sq_kernel(const float* __restrict__ xin, int ldx, float* __restrict__ sqb, int total) {
  int i = blockIdx.x * 256 + threadIdx.x;
  if (i >= total) return;
  const float* p = xin + (size_t)i * ldx;
  float s;
  if (C == 3) {
    s = 0.f;
    s = fmaf(p[0], p[0], s); s = fmaf(p[1], p[1], s); s = fmaf(p[2], p[2], s);
  } else {
    float4 a = make_float4(0.f, 0.f, 0.f, 0.f);
    for (int c = 0; c < C; c += 4) {
      float4 xv = *(const float4*)(p + c);
      a.x = fmaf(xv.x, xv.x, a.x); a.y = fmaf(xv.y, xv.y, a.y);
      a.z = fmaf(xv.z, xv.z, a.z); a.w = fmaf(xv.w, xv.w, a.w);
    }
    s = (a.x + a.y) + (a.z + a.w);
  }
  sqb[i] = s;
}

// ---------------- fused knn: distances + wave-level top-(K+1) ----------------
// Block = 256 threads = 4 waves, QB=4 queries. Distance phase: 256 threads
// strided over m, c-loop chunked by 16 floats with unroll 1 (no spills; round-3
// profile showed 1.3 GB/dispatch scratch traffic from full unroll @ 256 VGPR).
// Selection: wave w owns query w; shuffle butterfly per extraction.
template <int C>
__global__ __launch_bounds__(256, 4) void knn_kernel(
    const float* __restrict__ xin, int ldx, const float* __restrict__ sqb,
    int* __restrict__ idxout, int B, int N, int K) {
  constexpr int QB = 4;
  constexpr int CP = (C % 4 == 0) ? C : 4;
  __shared__ float dist[QB][2048];
  __shared__ float xq[QB][CP];
  const int tid = threadIdx.x;
  const int lane = tid & 63;
  const int wave = tid >> 6;
  const int b = blockIdx.y;
  const int n0 = blockIdx.x * QB;

  for (int i = tid; i < QB * C; i += 256) {
    int q = i / C, c = i % C;
    xq[q][c] = xin[((size_t)(b * N) + n0 + q) * ldx + c];
  }
  __syncthreads();
  float sqq[QB];
#pragma unroll
  for (int q = 0; q < QB; ++q) sqq[q] = sqb[b * N + n0 + q];

#pragma unroll 1
  for (int m = tid; m < N; m += 256) {
    const float* xm = xin + ((size_t)(b * N) + m) * ldx;
    float inner[QB];
    if (C == 3) {
      float x0 = xm[0], x1 = xm[1], x2 = xm[2];
#pragma unroll
      for (int q = 0; q < QB; ++q) {
        float s = 0.f;
        s = fmaf(x0, xq[q][0], s); s = fmaf(x1, xq[q][1], s); s = fmaf(x2, xq[q][2], s);
        inner[q] = s;
      }
    } else {
      float4 acc[QB];
#pragma unroll
      for (int q = 0; q < QB; ++q) acc[q] = make_float4(0.f, 0.f, 0.f, 0.f);
#pragma unroll 1
      for (int c0 = 0; c0 < C; c0 += 16) {
#pragma unroll
        for (int j = 0; j < 4; ++j) {
          float4 xv = *(const float4*)(xm + c0 + 4 * j);
#pragma unroll
          for (int q = 0; q < QB; ++q) {
            float4 qv = *(const float4*)&xq[q][c0 + 4 * j];
            acc[q].x = fmaf(xv.x, qv.x, acc[q].x);
            acc[q].y = fmaf(xv.y, qv.y, acc[q].y);
            acc[q].z = fmaf(xv.z, qv.z, acc[q].z);
            acc[q].w = fmaf(xv.w, qv.w, acc[q].w);
          }
        }
      }
#pragma unroll
      for (int q = 0; q < QB; ++q)
        inner[q] = (acc[q].x + acc[q].y) + (acc[q].z + acc[q].w);
    }
    float sqm = sqb[b * N + m];
#pragma unroll
    for (int q = 0; q < QB; ++q) {
      float t = sqq[q] - 2.f * inner[q];
      t = t + sqm;
      dist[q][m] = -t;
    }
  }
  __syncthreads();

  // ---- wave-level selection: wave owns query q = wave ----
  {
    const int q = wave;
    const int nq = n0 + q;
    float lv = NEG_INF;
    int lm = 0;
#pragma unroll 1
    for (int i = 0; i < 32; ++i) {
      int m = 64 * i + lane;
      float v = dist[q][m];
      if (v > lv) { lv = v; lm = m; }   // ascending m: strict > keeps min index
    }
#pragma unroll 1
    for (int sel = 0; sel <= K; ++sel) {
      float bv = lv;
      int bm = lm;
#pragma unroll
      for (int s = 1; s < 64; s <<= 1) {
        float ov = __shfl_xor(bv, s);
        int om = __shfl_xor(bm, s);
        if (ov > bv || (ov == bv && om < bm)) { bv = ov; bm = om; }
      }
      if (sel > 0 && lane == 0)
        idxout[((size_t)(b * N) + nq) * K + (sel - 1)] = bm;
      if ((bm & 63) == lane) {
        dist[q][bm] = NEG_INF;
        lv = NEG_INF; lm = 0;
#pragma unroll 1
        for (int i = 0; i < 32; ++i) {
          int m = 64 * i + lane;
          float v = dist[q][m];
          if (v > lv) { lv = v; lm = m; }
        }
      }
    }
  }
}

// ---------------- build [W2 ; W1-W2] from edge weight (O, 2C), fp32 ---------
__global__ void wcomb_build(const float* __restrict__ w, float* __restrict__ wc, int O, int C) {
  int i = blockIdx.x * 256 + threadIdx.x;
  if (i >= O * C) return;
  int o = i / C, c = i % C;
  float w1 = w[o * 2 * C + c];
  float w2 = w[o * 2 * C + C + c];
  wc[(size_t)o * C + c] = w2;                 // u rows
  wc[(size_t)(O + o) * C + c] = w1 - w2;      // v rows
}

// ---------------- fp32 C = A(MxK,lda) * B(NcxK)^T ---------------------------
__global__ __launch_bounds__(256) void gemm_abt(
    const float* __restrict__ A, int lda, const float* __restrict__ Bm,
    float* __restrict__ Cm, int ldc, int M, int Nc, int K) {
  __shared__ float As[16][65];
  __shared__ float Bs[16][65];
  const int tid = threadIdx.x;
  const int tx = tid & 15, ty = tid >> 4;
  const int n0 = blockIdx.x * 64;
  const int m0 = blockIdx.y * 64;
  float acc[4][4] = {};
  const int nkt = (K + 15) / 16;
  for (int kt = 0; kt < nkt; ++kt) {
    int k0 = kt * 16;
#pragma unroll
    for (int ph = 0; ph < 4; ++ph) {
      int idx = tid + 256 * ph;
      int k = idx & 15, mr = idx >> 4;
      float v = 0.f;
      if (k0 + k < K) v = A[(size_t)(m0 + mr) * lda + k0 + k];
      As[k][mr] = v;
    }
#pragma unroll
    for (int ph = 0; ph < 4; ++ph) {
      int idx = tid + 256 * ph;
      int k = idx & 15, nr = idx >> 4;
      float v = 0.f;
      if (k0 + k < K) v = Bm[(size_t)(n0 + nr) * K + k0 + k];
      Bs[k][nr] = v;
    }
    __syncthreads();
#pragma unroll
    for (int kk = 0; kk < 16; ++kk) {
      float av[4], bv[4];
#pragma unroll
      for (int r = 0; r < 4; ++r) av[r] = As[kk][4 * ty + r];
#pragma unroll
      for (int c = 0; c < 4; ++c) bv[c] = Bs[kk][4 * tx + c];
#pragma unroll
      for (int r = 0; r < 4; ++r)
#pragma unroll
        for (int c = 0; c < 4; ++c) acc[r][c] = fmaf(av[r], bv[c], acc[r][c]);
    }
    __syncthreads();
  }
#pragma unroll
  for (int r = 0; r < 4; ++r) {
    float4 v = make_float4(acc[r][0], acc[r][1], acc[r][2], acc[r][3]);
    *(float4*)&Cm[(size_t)(m0 + 4 * ty + r) * ldc + n0 + 4 * tx] = v;
  }
}

// ---------------- edge conv pass1: h = v_n + u_m; stats + max/min over k ----
__global__ void edge_pass1(const float* __restrict__ uv, const int* __restrict__ idx,
                           float* __restrict__ hmax, float* __restrict__ hmin,
                           float* __restrict__ part, int N, int O, int K) {
  int b = blockIdx.y, n = blockIdx.x, o = threadIdx.x;
  size_t row = (size_t)b * N + n;
  const int twoO = 2 * O;
  float vv = uv[row * twoO + O + o];
  const int* ib = idx + row * K;
  float mx = NEG_INF, mn = POS_INF, s = 0.f, ss = 0.f;
  for (int k = 0; k < K; ++k) {
    int m = ib[k];
    float h = vv + uv[((size_t)b * N + m) * twoO + o];
    mx = fmaxf(mx, h); mn = fminf(mn, h);
    s += h; ss = fmaf(h, h, ss);
  }
  hmax[row * O + o] = mx;
  hmin[row * O + o] = mn;
  __shared__ float2 red[256];
  red[o] = make_float2(s, ss);
  __syncthreads();
  int gsz = O >> 2;
  int lane = o & (gsz - 1);
  for (int off = gsz >> 1; off > 0; off >>= 1) {
    if (lane < off) { red[o].x += red[o + off].x; red[o].y += red[o + off].y; }
    __syncthreads();
  }
  if (lane == 0) {
    int g = o / gsz;
    part[row * 8 + g * 2] = red[o].x;
    part[row * 8 + g * 2 + 1] = red[o].y;
  }
}

__global__ void stats_reduce(const float* __restrict__ part, float* __restrict__ st, int N) {
  int g = blockIdx.x, b = blockIdx.y, tid = threadIdx.x;
  float s = 0.f, ss = 0.f;
  for (int n = tid; n < N; n += 256) {
    size_t base = ((size_t)b * N + n) * 8 + g * 2;
    s += part[base]; ss += part[base + 1];
  }
  __shared__ float2 red[256];
  red[tid] = make_float2(s, ss);
  __syncthreads();
  for (int off = 128; off > 0; off >>= 1) {
    if (tid < off) { red[tid].x += red[tid + off].x; red[tid].y += red[tid + off].y; }
    __syncthreads();
  }
  if (tid == 0) { st[(b * 4 + g) * 2] = red[0].x; st[(b * 4 + g) * 2 + 1] = red[0].y; }
}

__global__ void edge_pass2(const float* __restrict__ hmax, const float* __restrict__ hmin,
                           const float* __restrict__ st,
                           const float* __restrict__ gw, const float* __restrict__ gb,
                           float* __restrict__ outbase, int N, int O, int K, int coloff, int total) {
  int i = blockIdx.x * 256 + threadIdx.x;
  if (i >= total) return;
  int o = i % O;
  int n = (i / O) % N;
  int b = i / (O * N);
  int gsz = O >> 2;
  int g = o / gsz;
  float S = st[(b * 4 + g) * 2], SS = st[(b * 4 + g) * 2 + 1];
  float cnt = (float)N * (float)K * (float)gsz;
  float mean = S / cnt;
  float var = SS / cnt - mean * mean;
  float rs = rsqrtf(var + 1e-5f);
  float wf = gw[o], bf = gb[o];
  float Mv = (wf >= 0.f) ? hmax[i] : hmin[i];
  float val = (Mv - mean) * rs * wf + bf;
  outbase[((size_t)b * N + n) * 512 + coloff + o] = lk(val);
}

// ---------------- gn_seq stats ----------------
__global__ void seq_stats(const float* __restrict__ h, float* __restrict__ st16,
                          float* __restrict__ maxv, float* __restrict__ minv, int N) {
  int b = blockIdx.y;
  int tid = threadIdx.x;
  int c = blockIdx.x * 256 + tid;
  float mx = NEG_INF, mn = POS_INF, s = 0.f, ss = 0.f;
  for (int n = 0; n < N; ++n) {
    float v = h[((size_t)b * N + n) * 1024 + c];
    mx = fmaxf(mx, v); mn = fminf(mn, v);
    s += v; ss = fmaf(v, v, ss);
  }
  maxv[b * 1024 + c] = mx;
  minv[b * 1024 + c] = mn;
  __shared__ float2 red[256];
  red[tid] = make_float2(s, ss);
  __syncthreads();
  int lane = tid & 63;
  for (int off = 32; off > 0; off >>= 1) {
    if (lane < off) { red[tid].x += red[tid + off].x; red[tid].y += red[tid + off].y; }
    __syncthreads();
  }
  if (lane == 0) {
    int g = c >> 6;
    st16[(b * 16 + g) * 2] = red[tid].x;
    st16[(b * 16 + g) * 2 + 1] = red[tid].y;
  }
}

__global__ void seq_apply(const float* __restrict__ st16, const float* __restrict__ maxv,
                          const float* __restrict__ minv, const float* __restrict__ gw,
                          const float* __restrict__ gb, float* __restrict__ g, int N) {
  int i = blockIdx.x * 256 + threadIdx.x;
  if (i >= 8 * 1024) return;
  int b = i >> 10, c = i & 1023;
  int grp = c >> 6;
  float S = st16[(b * 16 + grp) * 2], SS = st16[(b * 16 + grp) * 2 + 1];
  float cnt = (float)N * 64.f;
  float mean = S / cnt;
  float var = SS / cnt - mean * mean;
  float rs = rsqrtf(var + 1e-5f);
  float wf = gw[c], bf = gb[c];
  float Mv = (wf >= 0.f) ? maxv[i] : minv[i];
  g[i] = lk((Mv - mean) * rs * wf + bf);
}

// ---------------- small MLP head ----------------
__global__ void fc_kernel(const float* __restrict__ in, const float* __restrict__ w,
                          const float* __restrict__ bias, float* __restrict__ z,
                          int Cin, int Cout) {
  int b = blockIdx.y;
  int o = blockIdx.x * 64 + threadIdx.x;
  if (o >= Cout) return;
  const float* ir = in + (size_t)b * Cin;
  const float* wr = w + (size_t)o * Cin;
  float acc = 0.f;
  for (int c = 0; c < Cin; ++c) acc = fmaf(ir[c], wr[c], acc);
  z[b * Cout + o] = acc + bias[o];
}

__global__ void ln_leaky(const float* __restrict__ z, const float* __restrict__ w,
                         const float* __restrict__ bias, float* __restrict__ out, int Cn) {
  int b = blockIdx.x, tid = threadIdx.x;
  const float* zr = z + (size_t)b * Cn;
  float s = 0.f, ss = 0.f;
  for (int o = tid; o < Cn; o += 256) { float v = zr[o]; s += v; ss = fmaf(v, v, ss); }
  __shared__ float2 red[256];
  red[tid] = make_float2(s, ss);
  __syncthreads();
  for (int off = 128; off > 0; off >>= 1) {
    if (tid < off) { red[tid].x += red[tid + off].x; red[tid].y += red[tid + off].y; }
    __syncthreads();
  }
  float mean = red[0].x / Cn;
  float var = red[0].y / Cn - mean * mean;
  float rs = rsqrtf(var + 1e-5f);
  for (int o = tid; o < Cn; o += 256) {
    float v = (zr[o] - mean) * rs * w[o] + bias[o];
    out[b * Cn + o] = lk(v);
  }
}

__global__ void final_fc(const float* __restrict__ in, const float* __restrict__ w,
                         const float* __restrict__ bias, void* __restrict__ out,
                         const int* __restrict__ flag) {
  int t = threadIdx.x;
  if (t >= 16) return;
  int b = t >> 1, j = t & 1;
  float acc = 0.f;
  for (int c = 0; c < 64; ++c) acc = fmaf(in[b * 64 + c], w[j * 64 + c], acc);
  acc += bias[j];
  if (*flag) ((__hip_bfloat16*)out)[t] = __float2bfloat16(acc);
  else       ((float*)out)[t] = acc;
}

// ---------------- host-side dispatch helpers -----------------------
static void launch_sq(int C, const float* xin, int ldx, float* sqb, int BN, hipStream_t s) {
  dim3 g((BN + 255) / 256);
  if (C == 3)       sq_kernel<3><<<g, 256, 0, s>>>(xin, ldx, sqb, BN);
  else if (C == 64) sq_kernel<64><<<g, 256, 0, s>>>(xin, ldx, sqb, BN);
  else              sq_kernel<128><<<g, 256, 0, s>>>(xin, ldx, sqb, BN);
}
static void launch_knn(int C, const float* xin, int ldx, const float* sqb, int* idx,
                       int B, int N, int K, hipStream_t s) {
  dim3 g(N / 4, B);
  if (C == 3)       knn_kernel<3><<<g, 256, 0, s>>>(xin, ldx, sqb, idx, B, N, K);
  else if (C == 64) knn_kernel<64><<<g, 256, 0, s>>>(xin, ldx, sqb, idx, B, N, K);
  else              knn_kernel<128><<<g, 256, 0, s>>>(xin, ldx, sqb, idx, B, N, K);
}

extern "C" void kernel_launch(void* const* d_in, const int* in_sizes, int n_in,
                              void* d_out, int out_size, void* d_ws, size_t ws_size,
                              hipStream_t stream) {
  (void)out_size; (void)ws_size;
  const int B = 8, N = 2048, KNN = 20;
  const int BN = B * N;

  float* base = (float*)d_ws;
  size_t off = 0;
  auto alloc = [&](size_t nf) { float* p = base + off; off += nf; return p; };

  int*   FLAG  = (int*)alloc(16);
  float* XF    = alloc((size_t)BN * 3);
  float* HCAT  = alloc((size_t)BN * 512);
  float* BIG   = alloc((size_t)BN * 1024);   // UV | HMAX | HMIN during edge phase; H1024 after
  float* UV    = BIG;
  float* HMAX  = BIG + (size_t)BN * 512;
  float* HMIN  = BIG + (size_t)BN * 768;
  float* H1024 = BIG;
  float* SQB   = alloc(BN);
  float* WCOMB = alloc((size_t)512 * 128);
  float* PART  = alloc((size_t)BN * 8);
  float* ST4   = alloc(64);
  float* ST16  = alloc(512);
  float* MAXV  = alloc(8 * 1024);
  float* MINV  = alloc(8 * 1024);
  float* GVEC  = alloc(8 * 1024);
  float* Z1 = alloc(8 * 512); float* A1v = alloc(8 * 512);
  float* Z2 = alloc(8 * 256); float* A2v = alloc(8 * 256);
  float* Z3 = alloc(8 * 64);  float* A3v = alloc(8 * 64);
  int*   IDX = (int*)alloc((size_t)BN * KNN);

  // converted fp32 weights
  ConvTable ct;
  float* conv_dst[30];
  for (int i = 0; i < 30; ++i) {
    int n = in_sizes[i];
    conv_dst[i] = alloc((size_t)((n + 15) & ~15));
    ct.src[i] = d_in[i];
    ct.dst[i] = conv_dst[i];
    ct.n[i] = n;
  }
  ct.dst[0] = XF; ct.n[0] = BN * 3;   // x goes straight to XF

  const float* W_[4]  = {conv_dst[1], conv_dst[4], conv_dst[7], conv_dst[10]};
  const float* GW_[4] = {conv_dst[2], conv_dst[5], conv_dst[8], conv_dst[11]};
  const float* GB_[4] = {conv_dst[3], conv_dst[6], conv_dst[9], conv_dst[12]};
  const float* WM = conv_dst[13];
  const float* GMW = conv_dst[14], *GMB = conv_dst[15];
  const float* FC1W = conv_dst[16], *FC1B = conv_dst[17], *LN1W = conv_dst[18], *LN1B = conv_dst[19];
  const float* FC2W = conv_dst[20], *FC2B = conv_dst[21], *LN2W = conv_dst[22], *LN2B = conv_dst[23];
  const float* FC3W = conv_dst[24], *FC3B = conv_dst[25], *LN3W = conv_dst[26], *LN3B = conv_dst[27];
  const float* FC4W = conv_dst[28], *FC4B = conv_dst[29];

  detect_dtype<<<dim3(1), 64, 0, stream>>>((const unsigned short*)d_in[0], FLAG);
  conv_all<<<dim3(2048, 30), 256, 0, stream>>>(ct, FLAG);

  const int Cs[4]     = {3, 64, 64, 128};
  const int Os[4]     = {64, 64, 128, 256};
  const int incol[4]  = {0, 0, 64, 128};
  const int outcol[4] = {0, 64, 128, 256};

  for (int l = 0; l < 4; ++l) {
    const int C = Cs[l], O = Os[l], twoO = 2 * O;
    const float* xin = (l == 0) ? XF : (HCAT + incol[l]);
    const int ldx = (l == 0) ? 3 : 512;

    launch_sq(C, xin, ldx, SQB, BN, stream);
    launch_knn(C, xin, ldx, SQB, IDX, B, N, KNN, stream);
    wcomb_build<<<dim3((O * C + 255) / 256), 256, 0, stream>>>(W_[l], WCOMB, O, C);
    gemm_abt<<<dim3(twoO / 64, BN / 64), 256, 0, stream>>>(xin, ldx, WCOMB, UV, twoO, BN, twoO, C);
    edge_pass1<<<dim3(N, B), O, 0, stream>>>(UV, IDX, HMAX, HMIN, PART, N, O, KNN);
    stats_reduce<<<dim3(4, B), 256, 0, stream>>>(PART, ST4, N);
    int tot = BN * O;
    edge_pass2<<<dim3((tot + 255) / 256), 256, 0, stream>>>(HMAX, HMIN, ST4, GW_[l], GB_[l],
                                                            HCAT, N, O, KNN, outcol[l], tot);
  }

  gemm_abt<<<dim3(1024 / 64, BN / 64), 256, 0, stream>>>(HCAT, 512, WM, H1024, 1024, BN, 1024, 512);
  seq_stats<<<dim3(4, B), 256, 0, stream>>>(H1024, ST16, MAXV, MINV, N);
  seq_apply<<<dim3(32), 256, 0, stream>>>(ST16, MAXV, MINV, GMW, GMB, GVEC, N);

  fc_kernel<<<dim3(8, 8), 64, 0, stream>>>(GVEC, FC1W, FC1B, Z1, 1024, 512);
  ln_leaky<<<dim3(8), 256, 0, stream>>>(Z1, LN1W, LN1B, A1v, 512);
  fc_kernel<<<dim3(4, 8), 64, 0, stream>>>(A1v, FC2W, FC2B, Z2, 512, 256);
  ln_leaky<<<dim3(8), 256, 0, stream>>>(Z2, LN2W, LN2B, A2v, 256);
  fc_kernel<<<dim3(1, 8), 64, 0, stream>>>(A2v, FC3W, FC3B, Z3, 256, 64);
  ln_leaky<<<dim3(8), 256, 0, stream>>>(Z3, LN3W, LN3B, A3v, 64);
  final_fc<<<dim3(1), 64, 0, stream>>>(A3v, FC4W, FC4B, d_out, FLAG);
}

// Round 5
// 2664.258 us; speedup vs baseline: 4.5061x; 1.1068x over previous
//
#include <hip/hip_runtime.h>
#include <hip/hip_bf16.h>

// DGCNN forward on MI355X. Dtype-adaptive: a device probe detects whether the
// harness buffers are fp32 (reference dtypes) or bf16; everything is converted
// to fp32 in d_ws and computed in fp32. B=8, N=2048, K=20.

#define NEG_INF (-3.402823466e38f)
#define POS_INF (3.402823466e38f)

__device__ __forceinline__ float lk(float x) { return x > 0.f ? x : 0.2f * x; }

// ---------------- dtype probe: 1 = bf16, 0 = fp32 ----------------
__global__ void detect_dtype(const unsigned short* __restrict__ x16, int* __restrict__ flag) {
  if (threadIdx.x == 0 && blockIdx.x == 0) {
    int sane = 0;
    for (int i = 0; i < 64; ++i) {
      unsigned short u = x16[2 * i];   // low half of float i if fp32; element 2i if bf16
      int e = (u >> 7) & 0xff;
      if (e == 0 || (e >= 90 && e <= 140)) ++sane;
    }
    *flag = (sane >= 32) ? 1 : 0;
  }
}

// ---------------- batched convert-to-fp32 of all inputs ----------------
struct ConvTable {
  const void* src[30];
  float* dst[30];
  int n[30];
};

__global__ void conv_all(ConvTable t, const int* __restrict__ flag) {
  int e = blockIdx.y;
  int i = blockIdx.x * 256 + threadIdx.x;
  if (i >= t.n[e]) return;
  float v;
  if (*flag) v = __bfloat162float(((const __hip_bfloat16*)t.src[e])[i]);
  else       v = ((const float*)t.src[e])[i];
  t.dst[e][i] = v;
}

// ---------------- squared norms (accumulation order must match knn inner) ----
template <int C>
__global__ void sq_kernel(const float* __restrict__ xin, int ldx, float* __restrict__ sqb, int total) {
  int i = blockIdx.x * 256 + threadIdx.x;
  if (i >= total) return;
  const float* p = xin + (size_t)i * ldx;
  float s;
  if (C == 3) {
    s = 0.f;
    s = fmaf(p[0], p[0], s); s = fmaf(p[1], p[1], s); s = fmaf(p[2], p[2], s);
  } else {
    float4 a = make_float4(0.f, 0.f, 0.f, 0.f);
    for (int c = 0; c < C; c += 4) {
      float4 xv = *(const float4*)(p + c);
      a.x = fmaf(xv.x, xv.x, a.x); a.y = fmaf(xv.y, xv.y, a.y);
      a.z = fmaf(xv.z, xv.z, a.z); a.w = fmaf(xv.w, xv.w, a.w);
    }
    s = (a.x + a.y) + (a.z + a.w);
  }
  sqb[i] = s;
}

// ---------------- fused knn: distances + wave-level top-(K+1) ----------------
// Block = 256 threads = 4 waves, QB=4 queries. Distance phase: 256 threads
// strided over m, c-loop chunked (no spills). Selection: wave w owns query w;
// each lane holds its 32 strided dist values in REGISTERS (round-4 profile:
// the serial per-round LDS rescan was ~80k cyc/block = the whole kernel).
// Per round: unrolled register argmax + shuffle butterfly + predicated
// register invalidation. Tie-break = (max value, min index) as lax.top_k.
template <int C>
__global__ __launch_bounds__(256, 4) void knn_kernel(
    const float* __restrict__ xin, int ldx, const float* __restrict__ sqb,
    int* __restrict__ idxout, int B, int N, int K) {
  constexpr int QB = 4;
  constexpr int CP = (C % 4 == 0) ? C : 4;
  __shared__ float dist[QB][2048];
  __shared__ float xq[QB][CP];
  const int tid = threadIdx.x;
  const int lane = tid & 63;
  const int wave = tid >> 6;
  const int b = blockIdx.y;
  const int n0 = blockIdx.x * QB;

  for (int i = tid; i < QB * C; i += 256) {
    int q = i / C, c = i % C;
    xq[q][c] = xin[((size_t)(b * N) + n0 + q) * ldx + c];
  }
  __syncthreads();
  float sqq[QB];
#pragma unroll
  for (int q = 0; q < QB; ++q) sqq[q] = sqb[b * N + n0 + q];

#pragma unroll 1
  for (int m = tid; m < N; m += 256) {
    const float* xm = xin + ((size_t)(b * N) + m) * ldx;
    float inner[QB];
    if (C == 3) {
      float x0 = xm[0], x1 = xm[1], x2 = xm[2];
#pragma unroll
      for (int q = 0; q < QB; ++q) {
        float s = 0.f;
        s = fmaf(x0, xq[q][0], s); s = fmaf(x1, xq[q][1], s); s = fmaf(x2, xq[q][2], s);
        inner[q] = s;
      }
    } else {
      float4 acc[QB];
#pragma unroll
      for (int q = 0; q < QB; ++q) acc[q] = make_float4(0.f, 0.f, 0.f, 0.f);
#pragma unroll 1
      for (int c0 = 0; c0 < C; c0 += 16) {
#pragma unroll
        for (int j = 0; j < 4; ++j) {
          float4 xv = *(const float4*)(xm + c0 + 4 * j);
#pragma unroll
          for (int q = 0; q < QB; ++q) {
            float4 qv = *(const float4*)&xq[q][c0 + 4 * j];
            acc[q].x = fmaf(xv.x, qv.x, acc[q].x);
            acc[q].y = fmaf(xv.y, qv.y, acc[q].y);
            acc[q].z = fmaf(xv.z, qv.z, acc[q].z);
            acc[q].w = fmaf(xv.w, qv.w, acc[q].w);
          }
        }
      }
#pragma unroll
      for (int q = 0; q < QB; ++q)
        inner[q] = (acc[q].x + acc[q].y) + (acc[q].z + acc[q].w);
    }
    float sqm = sqb[b * N + m];
#pragma unroll
    for (int q = 0; q < QB; ++q) {
      float t = sqq[q] - 2.f * inner[q];
      t = t + sqm;
      dist[q][m] = -t;
    }
  }
  __syncthreads();

  // ---- wave-level selection: wave owns query q = wave; dist in registers ----
  {
    const int q = wave;
    const int nq = n0 + q;
    float v[32];
#pragma unroll
    for (int i = 0; i < 32; ++i) v[i] = dist[q][64 * i + lane];   // pipelined burst

    float lv = NEG_INF;
    int lm = 0;
#pragma unroll
    for (int i = 0; i < 32; ++i) {
      int m = 64 * i + lane;
      if (v[i] > lv) { lv = v[i]; lm = m; }   // ascending m: strict > keeps min index
    }
#pragma unroll 1
    for (int sel = 0; sel <= K; ++sel) {
      float bv = lv;
      int bm = lm;
#pragma unroll
      for (int s = 1; s < 64; s <<= 1) {
        float ov = __shfl_xor(bv, s);
        int om = __shfl_xor(bm, s);
        if (ov > bv || (ov == bv && om < bm)) { bv = ov; bm = om; }
      }
      if (sel > 0 && lane == 0)
        idxout[((size_t)(b * N) + nq) * K + (sel - 1)] = bm;
      // invalidate winner in registers (bm is wave-uniform; matches one lane)
#pragma unroll
      for (int i = 0; i < 32; ++i)
        if (64 * i + lane == bm) v[i] = NEG_INF;
      // winner lane recomputes its local argmax (exec-masked for others)
      if ((bm & 63) == lane) {
        lv = NEG_INF; lm = 0;
#pragma unroll
        for (int i = 0; i < 32; ++i) {
          int m = 64 * i + lane;
          if (v[i] > lv) { lv = v[i]; lm = m; }
        }
      }
    }
  }
}

// ---------------- build [W2 ; W1-W2] from edge weight (O, 2C), fp32 ---------
__global__ void wcomb_build(const float* __restrict__ w, float* __restrict__ wc, int O, int C) {
  int i = blockIdx.x * 256 + threadIdx.x;
  if (i >= O * C) return;
  int o = i / C, c = i % C;
  float w1 = w[o * 2 * C + c];
  float w2 = w[o * 2 * C + C + c];
  wc[(size_t)o * C + c] = w2;                 // u rows
  wc[(size_t)(O + o) * C + c] = w1 - w2;      // v rows
}

// ---------------- fp32 C = A(MxK,lda) * B(NcxK)^T ---------------------------
__global__ __launch_bounds__(256) void gemm_abt(
    const float* __restrict__ A, int lda, const float* __restrict__ Bm,
    float* __restrict__ Cm, int ldc, int M, int Nc, int K) {
  __shared__ float As[16][65];
  __shared__ float Bs[16][65];
  const int tid = threadIdx.x;
  const int tx = tid & 15, ty = tid >> 4;
  const int n0 = blockIdx.x * 64;
  const int m0 = blockIdx.y * 64;
  float acc[4][4] = {};
  const int nkt = (K + 15) / 16;
  for (int kt = 0; kt < nkt; ++kt) {
    int k0 = kt * 16;
#pragma unroll
    for (int ph = 0; ph < 4; ++ph) {
      int idx = tid + 256 * ph;
      int k = idx & 15, mr = idx >> 4;
      float v = 0.f;
      if (k0 + k < K) v = A[(size_t)(m0 + mr) * lda + k0 + k];
      As[k][mr] = v;
    }
#pragma unroll
    for (int ph = 0; ph < 4; ++ph) {
      int idx = tid + 256 * ph;
      int k = idx & 15, nr = idx >> 4;
      float v = 0.f;
      if (k0 + k < K) v = Bm[(size_t)(n0 + nr) * K + k0 + k];
      Bs[k][nr] = v;
    }
    __syncthreads();
#pragma unroll
    for (int kk = 0; kk < 16; ++kk) {
      float av[4], bv[4];
#pragma unroll
      for (int r = 0; r < 4; ++r) av[r] = As[kk][4 * ty + r];
#pragma unroll
      for (int c = 0; c < 4; ++c) bv[c] = Bs[kk][4 * tx + c];
#pragma unroll
      for (int r = 0; r < 4; ++r)
#pragma unroll
        for (int c = 0; c < 4; ++c) acc[r][c] = fmaf(av[r], bv[c], acc[r][c]);
    }
    __syncthreads();
  }
#pragma unroll
  for (int r = 0; r < 4; ++r) {
    float4 v = make_float4(acc[r][0], acc[r][1], acc[r][2], acc[r][3]);
    *(float4*)&Cm[(size_t)(m0 + 4 * ty + r) * ldc + n0 + 4 * tx] = v;
  }
}

// ---------------- edge conv pass1: h = v_n + u_m; stats + max/min over k ----
__global__ void edge_pass1(const float* __restrict__ uv, const int* __restrict__ idx,
                           float* __restrict__ hmax, float* __restrict__ hmin,
                           float* __restrict__ part, int N, int O, int K) {
  int b = blockIdx.y, n = blockIdx.x, o = threadIdx.x;
  size_t row = (size_t)b * N + n;
  const int twoO = 2 * O;
  float vv = uv[row * twoO + O + o];
  const int* ib = idx + row * K;
  float mx = NEG_INF, mn = POS_INF, s = 0.f, ss = 0.f;
  for (int k = 0; k < K; ++k) {
    int m = ib[k];
    float h = vv + uv[((size_t)b * N + m) * twoO + o];
    mx = fmaxf(mx, h); mn = fminf(mn, h);
    s += h; ss = fmaf(h, h, ss);
  }
  hmax[row * O + o] = mx;
  hmin[row * O + o] = mn;
  __shared__ float2 red[256];
  red[o] = make_float2(s, ss);
  __syncthreads();
  int gsz = O >> 2;
  int lane = o & (gsz - 1);
  for (int off = gsz >> 1; off > 0; off >>= 1) {
    if (lane < off) { red[o].x += red[o + off].x; red[o].y += red[o + off].y; }
    __syncthreads();
  }
  if (lane == 0) {
    int g = o / gsz;
    part[row * 8 + g * 2] = red[o].x;
    part[row * 8 + g * 2 + 1] = red[o].y;
  }
}

__global__ void stats_reduce(const float* __restrict__ part, float* __restrict__ st, int N) {
  int g = blockIdx.x, b = blockIdx.y, tid = threadIdx.x;
  float s = 0.f, ss = 0.f;
  for (int n = tid; n < N; n += 256) {
    size_t base = ((size_t)b * N + n) * 8 + g * 2;
    s += part[base]; ss += part[base + 1];
  }
  __shared__ float2 red[256];
  red[tid] = make_float2(s, ss);
  __syncthreads();
  for (int off = 128; off > 0; off >>= 1) {
    if (tid < off) { red[tid].x += red[tid + off].x; red[tid].y += red[tid + off].y; }
    __syncthreads();
  }
  if (tid == 0) { st[(b * 4 + g) * 2] = red[0].x; st[(b * 4 + g) * 2 + 1] = red[0].y; }
}

__global__ void edge_pass2(const float* __restrict__ hmax, const float* __restrict__ hmin,
                           const float* __restrict__ st,
                           const float* __restrict__ gw, const float* __restrict__ gb,
                           float* __restrict__ outbase, int N, int O, int K, int coloff, int total) {
  int i = blockIdx.x * 256 + threadIdx.x;
  if (i >= total) return;
  int o = i % O;
  int n = (i / O) % N;
  int b = i / (O * N);
  int gsz = O >> 2;
  int g = o / gsz;
  float S = st[(b * 4 + g) * 2], SS = st[(b * 4 + g) * 2 + 1];
  float cnt = (float)N * (float)K * (float)gsz;
  float mean = S / cnt;
  float var = SS / cnt - mean * mean;
  float rs = rsqrtf(var + 1e-5f);
  float wf = gw[o], bf = gb[o];
  float Mv = (wf >= 0.f) ? hmax[i] : hmin[i];
  float val = (Mv - mean) * rs * wf + bf;
  outbase[((size_t)b * N + n) * 512 + coloff + o] = lk(val);
}

// ---------------- gn_seq stats ----------------
__global__ void seq_stats(const float* __restrict__ h, float* __restrict__ st16,
                          float* __restrict__ maxv, float* __restrict__ minv, int N) {
  int b = blockIdx.y;
  int tid = threadIdx.x;
  int c = blockIdx.x * 256 + tid;
  float mx = NEG_INF, mn = POS_INF, s = 0.f, ss = 0.f;
  for (int n = 0; n < N; ++n) {
    float v = h[((size_t)b * N + n) * 1024 + c];
    mx = fmaxf(mx, v); mn = fminf(mn, v);
    s += v; ss = fmaf(v, v, ss);
  }
  maxv[b * 1024 + c] = mx;
  minv[b * 1024 + c] = mn;
  __shared__ float2 red[256];
  red[tid] = make_float2(s, ss);
  __syncthreads();
  int lane = tid & 63;
  for (int off = 32; off > 0; off >>= 1) {
    if (lane < off) { red[tid].x += red[tid + off].x; red[tid].y += red[tid + off].y; }
    __syncthreads();
  }
  if (lane == 0) {
    int g = c >> 6;
    st16[(b * 16 + g) * 2] = red[tid].x;
    st16[(b * 16 + g) * 2 + 1] = red[tid].y;
  }
}

__global__ void seq_apply(const float* __restrict__ st16, const float* __restrict__ maxv,
                          const float* __restrict__ minv, const float* __restrict__ gw,
                          const float* __restrict__ gb, float* __restrict__ g, int N) {
  int i = blockIdx.x * 256 + threadIdx.x;
  if (i >= 8 * 1024) return;
  int b = i >> 10, c = i & 1023;
  int grp = c >> 6;
  float S = st16[(b * 16 + grp) * 2], SS = st16[(b * 16 + grp) * 2 + 1];
  float cnt = (float)N * 64.f;
  float mean = S / cnt;
  float var = SS / cnt - mean * mean;
  float rs = rsqrtf(var + 1e-5f);
  float wf = gw[c], bf = gb[c];
  float Mv = (wf >= 0.f) ? maxv[i] : minv[i];
  g[i] = lk((Mv - mean) * rs * wf + bf);
}

// ---------------- small MLP head ----------------
__global__ void fc_kernel(const float* __restrict__ in, const float* __restrict__ w,
                          const float* __restrict__ bias, float* __restrict__ z,
                          int Cin, int Cout) {
  int b = blockIdx.y;
  int o = blockIdx.x * 64 + threadIdx.x;
  if (o >= Cout) return;
  const float* ir = in + (size_t)b * Cin;
  const float* wr = w + (size_t)o * Cin;
  float acc = 0.f;
  for (int c = 0; c < Cin; ++c) acc = fmaf(ir[c], wr[c], acc);
  z[b * Cout + o] = acc + bias[o];
}

__global__ void ln_leaky(const float* __restrict__ z, const float* __restrict__ w,
                         const float* __restrict__ bias, float* __restrict__ out, int Cn) {
  int b = blockIdx.x, tid = threadIdx.x;
  const float* zr = z + (size_t)b * Cn;
  float s = 0.f, ss = 0.f;
  for (int o = tid; o < Cn; o += 256) { float v = zr[o]; s += v; ss = fmaf(v, v, ss); }
  __shared__ float2 red[256];
  red[tid] = make_float2(s, ss);
  __syncthreads();
  for (int off = 128; off > 0; off >>= 1) {
    if (tid < off) { red[tid].x += red[tid + off].x; red[tid].y += red[tid + off].y; }
    __syncthreads();
  }
  float mean = red[0].x / Cn;
  float var = red[0].y / Cn - mean * mean;
  float rs = rsqrtf(var + 1e-5f);
  for (int o = tid; o < Cn; o += 256) {
    float v = (zr[o] - mean) * rs * w[o] + bias[o];
    out[b * Cn + o] = lk(v);
  }
}

__global__ void final_fc(const float* __restrict__ in, const float* __restrict__ w,
                         const float* __restrict__ bias, void* __restrict__ out,
                         const int* __restrict__ flag) {
  int t = threadIdx.x;
  if (t >= 16) return;
  int b = t >> 1, j = t & 1;
  float acc = 0.f;
  for (int c = 0; c < 64; ++c) acc = fmaf(in[b * 64 + c], w[j * 64 + c], acc);
  acc += bias[j];
  if (*flag) ((__hip_bfloat16*)out)[t] = __float2bfloat16(acc);
  else       ((float*)out)[t] = acc;
}

// ---------------- host-side dispatch helpers -----------------------
static void launch_sq(int C, const float* xin, int ldx, float* sqb, int BN, hipStream_t s) {
  dim3 g((BN + 255) / 256);
  if (C == 3)       sq_kernel<3><<<g, 256, 0, s>>>(xin, ldx, sqb, BN);
  else if (C == 64) sq_kernel<64><<<g, 256, 0, s>>>(xin, ldx, sqb, BN);
  else              sq_kernel<128><<<g, 256, 0, s>>>(xin, ldx, sqb, BN);
}
static void launch_knn(int C, const float* xin, int ldx, const float* sqb, int* idx,
                       int B, int N, int K, hipStream_t s) {
  dim3 g(N / 4, B);
  if (C == 3)       knn_kernel<3><<<g, 256, 0, s>>>(xin, ldx, sqb, idx, B, N, K);
  else if (C == 64) knn_kernel<64><<<g, 256, 0, s>>>(xin, ldx, sqb, idx, B, N, K);
  else              knn_kernel<128><<<g, 256, 0, s>>>(xin, ldx, sqb, idx, B, N, K);
}

extern "C" void kernel_launch(void* const* d_in, const int* in_sizes, int n_in,
                              void* d_out, int out_size, void* d_ws, size_t ws_size,
                              hipStream_t stream) {
  (void)out_size; (void)ws_size;
  const int B = 8, N = 2048, KNN = 20;
  const int BN = B * N;

  float* base = (float*)d_ws;
  size_t off = 0;
  auto alloc = [&](size_t nf) { float* p = base + off; off += nf; return p; };

  int*   FLAG  = (int*)alloc(16);
  float* XF    = alloc((size_t)BN * 3);
  float* HCAT  = alloc((size_t)BN * 512);
  float* BIG   = alloc((size_t)BN * 1024);   // UV | HMAX | HMIN during edge phase; H1024 after
  float* UV    = BIG;
  float* HMAX  = BIG + (size_t)BN * 512;
  float* HMIN  = BIG + (size_t)BN * 768;
  float* H1024 = BIG;
  float* SQB   = alloc(BN);
  float* WCOMB = alloc((size_t)512 * 128);
  float* PART  = alloc((size_t)BN * 8);
  float* ST4   = alloc(64);
  float* ST16  = alloc(512);
  float* MAXV  = alloc(8 * 1024);
  float* MINV  = alloc(8 * 1024);
  float* GVEC  = alloc(8 * 1024);
  float* Z1 = alloc(8 * 512); float* A1v = alloc(8 * 512);
  float* Z2 = alloc(8 * 256); float* A2v = alloc(8 * 256);
  float* Z3 = alloc(8 * 64);  float* A3v = alloc(8 * 64);
  int*   IDX = (int*)alloc((size_t)BN * KNN);

  // converted fp32 weights
  ConvTable ct;
  float* conv_dst[30];
  for (int i = 0; i < 30; ++i) {
    int n = in_sizes[i];
    conv_dst[i] = alloc((size_t)((n + 15) & ~15));
    ct.src[i] = d_in[i];
    ct.dst[i] = conv_dst[i];
    ct.n[i] = n;
  }
  ct.dst[0] = XF; ct.n[0] = BN * 3;   // x goes straight to XF

  const float* W_[4]  = {conv_dst[1], conv_dst[4], conv_dst[7], conv_dst[10]};
  const float* GW_[4] = {conv_dst[2], conv_dst[5], conv_dst[8], conv_dst[11]};
  const float* GB_[4] = {conv_dst[3], conv_dst[6], conv_dst[9], conv_dst[12]};
  const float* WM = conv_dst[13];
  const float* GMW = conv_dst[14], *GMB = conv_dst[15];
  const float* FC1W = conv_dst[16], *FC1B = conv_dst[17], *LN1W = conv_dst[18], *LN1B = conv_dst[19];
  const float* FC2W = conv_dst[20], *FC2B = conv_dst[21], *LN2W = conv_dst[22], *LN2B = conv_dst[23];
  const float* FC3W = conv_dst[24], *FC3B = conv_dst[25], *LN3W = conv_dst[26], *LN3B = conv_dst[27];
  const float* FC4W = conv_dst[28], *FC4B = conv_dst[29];

  detect_dtype<<<dim3(1), 64, 0, stream>>>((const unsigned short*)d_in[0], FLAG);
  conv_all<<<dim3(2048, 30), 256, 0, stream>>>(ct, FLAG);

  const int Cs[4]     = {3, 64, 64, 128};
  const int Os[4]     = {64, 64, 128, 256};
  const int incol[4]  = {0, 0, 64, 128};
  const int outcol[4] = {0, 64, 128, 256};

  for (int l = 0; l < 4; ++l) {
    const int C = Cs[l], O = Os[l], twoO = 2 * O;
    const float* xin = (l == 0) ? XF : (HCAT + incol[l]);
    const int ldx = (l == 0) ? 3 : 512;

    launch_sq(C, xin, ldx, SQB, BN, stream);
    launch_knn(C, xin, ldx, SQB, IDX, B, N, KNN, stream);
    wcomb_build<<<dim3((O * C + 255) / 256), 256, 0, stream>>>(W_[l], WCOMB, O, C);
    gemm_abt<<<dim3(twoO / 64, BN / 64), 256, 0, stream>>>(xin, ldx, WCOMB, UV, twoO, BN, twoO, C);
    edge_pass1<<<dim3(N, B), O, 0, stream>>>(UV, IDX, HMAX, HMIN, PART, N, O, KNN);
    stats_reduce<<<dim3(4, B), 256, 0, stream>>>(PART, ST4, N);
    int tot = BN * O;
    edge_pass2<<<dim3((tot + 255) / 256), 256, 0, stream>>>(HMAX, HMIN, ST4, GW_[l], GB_[l],
                                                            HCAT, N, O, KNN, outcol[l], tot);
  }

  gemm_abt<<<dim3(1024 / 64, BN / 64), 256, 0, stream>>>(HCAT, 512, WM, H1024, 1024, BN, 1024, 512);
  seq_stats<<<dim3(4, B), 256, 0, stream>>>(H1024, ST16, MAXV, MINV, N);
  seq_apply<<<dim3(32), 256, 0, stream>>>(ST16, MAXV, MINV, GMW, GMB, GVEC, N);

  fc_kernel<<<dim3(8, 8), 64, 0, stream>>>(GVEC, FC1W, FC1B, Z1, 1024, 512);
  ln_leaky<<<dim3(8), 256, 0, stream>>>(Z1, LN1W, LN1B, A1v, 512);
  fc_kernel<<<dim3(4, 8), 64, 0, stream>>>(A1v, FC2W, FC2B, Z2, 512, 256);
  ln_leaky<<<dim3(8), 256, 0, stream>>>(Z2, LN2W, LN2B, A2v, 256);
  fc_kernel<<<dim3(1, 8), 64, 0, stream>>>(A2v, FC3W, FC3B, Z3, 256, 64);
  ln_leaky<<<dim3(8), 256, 0, stream>>>(Z3, LN3W, LN3B, A3v, 64);
  final_fc<<<dim3(1), 64, 0, stream>>>(A3v, FC4W, FC4B, d_out, FLAG);
}

// Round 6
// 2013.364 us; speedup vs baseline: 5.9628x; 1.3233x over previous
//
#include <hip/hip_runtime.h>
#include <hip/hip_bf16.h>

// DGCNN forward on MI355X. Dtype-adaptive: a device probe detects whether the
// harness buffers are fp32 (reference dtypes) or bf16; everything is converted
// to fp32 in d_ws and computed in fp32. B=8, N=2048, K=20.

#define NEG_INF (-3.402823466e38f)
#define POS_INF (3.402823466e38f)

__device__ __forceinline__ float lk(float x) { return x > 0.f ? x : 0.2f * x; }

// ---------------- dtype probe: 1 = bf16, 0 = fp32 ----------------
__global__ void detect_dtype(const unsigned short* __restrict__ x16, int* __restrict__ flag) {
  if (threadIdx.x == 0 && blockIdx.x == 0) {
    int sane = 0;
    for (int i = 0; i < 64; ++i) {
      unsigned short u = x16[2 * i];   // low half of float i if fp32; element 2i if bf16
      int e = (u >> 7) & 0xff;
      if (e == 0 || (e >= 90 && e <= 140)) ++sane;
    }
    *flag = (sane >= 32) ? 1 : 0;
  }
}

// ---------------- batched convert-to-fp32 of all inputs ----------------
struct ConvTable {
  const void* src[30];
  float* dst[30];
  int n[30];
};

__global__ void conv_all(ConvTable t, const int* __restrict__ flag) {
  int e = blockIdx.y;
  int i = blockIdx.x * 256 + threadIdx.x;
  if (i >= t.n[e]) return;
  float v;
  if (*flag) v = __bfloat162float(((const __hip_bfloat16*)t.src[e])[i]);
  else       v = ((const float*)t.src[e])[i];
  t.dst[e][i] = v;
}

// ---------------- squared norms (accumulation order must match knn inner) ----
template <int C>
__global__ void sq_kernel(const float* __restrict__ xin, int ldx, float* __restrict__ sqb, int total) {
  int i = blockIdx.x * 256 + threadIdx.x;
  if (i >= total) return;
  const float* p = xin + (size_t)i * ldx;
  float s;
  if (C == 3) {
    s = 0.f;
    s = fmaf(p[0], p[0], s); s = fmaf(p[1], p[1], s); s = fmaf(p[2], p[2], s);
  } else {
    float4 a = make_float4(0.f, 0.f, 0.f, 0.f);
    for (int c = 0; c < C; c += 4) {
      float4 xv = *(const float4*)(p + c);
      a.x = fmaf(xv.x, xv.x, a.x); a.y = fmaf(xv.y, xv.y, a.y);
      a.z = fmaf(xv.z, xv.z, a.z); a.w = fmaf(xv.w, xv.w, a.w);
    }
    s = (a.x + a.y) + (a.z + a.w);
  }
  sqb[i] = s;
}

// ---------------- fused knn: distances + wave-level top-(K+1) ----------------
// Block = 256 threads = 4 waves, QB=4 queries. Distance phase: 256 threads
// strided over m, c-loop chunked (no spills). Selection: wave w owns query w;
// each lane holds its 32 strided dist values in REGISTERS. Per round:
// unrolled register argmax + shuffle butterfly + predicated register
// invalidation. Tie-break = (max value, min index) as lax.top_k.
template <int C>
__global__ __launch_bounds__(256, 4) void knn_kernel(
    const float* __restrict__ xin, int ldx, const float* __restrict__ sqb,
    int* __restrict__ idxout, int B, int N, int K) {
  constexpr int QB = 4;
  constexpr int CP = (C % 4 == 0) ? C : 4;
  __shared__ float dist[QB][2048];
  __shared__ float xq[QB][CP];
  const int tid = threadIdx.x;
  const int lane = tid & 63;
  const int wave = tid >> 6;
  const int b = blockIdx.y;
  const int n0 = blockIdx.x * QB;

  for (int i = tid; i < QB * C; i += 256) {
    int q = i / C, c = i % C;
    xq[q][c] = xin[((size_t)(b * N) + n0 + q) * ldx + c];
  }
  __syncthreads();
  float sqq[QB];
#pragma unroll
  for (int q = 0; q < QB; ++q) sqq[q] = sqb[b * N + n0 + q];

#pragma unroll 1
  for (int m = tid; m < N; m += 256) {
    const float* xm = xin + ((size_t)(b * N) + m) * ldx;
    float inner[QB];
    if (C == 3) {
      float x0 = xm[0], x1 = xm[1], x2 = xm[2];
#pragma unroll
      for (int q = 0; q < QB; ++q) {
        float s = 0.f;
        s = fmaf(x0, xq[q][0], s); s = fmaf(x1, xq[q][1], s); s = fmaf(x2, xq[q][2], s);
        inner[q] = s;
      }
    } else {
      float4 acc[QB];
#pragma unroll
      for (int q = 0; q < QB; ++q) acc[q] = make_float4(0.f, 0.f, 0.f, 0.f);
#pragma unroll 1
      for (int c0 = 0; c0 < C; c0 += 16) {
#pragma unroll
        for (int j = 0; j < 4; ++j) {
          float4 xv = *(const float4*)(xm + c0 + 4 * j);
#pragma unroll
          for (int q = 0; q < QB; ++q) {
            float4 qv = *(const float4*)&xq[q][c0 + 4 * j];
            acc[q].x = fmaf(xv.x, qv.x, acc[q].x);
            acc[q].y = fmaf(xv.y, qv.y, acc[q].y);
            acc[q].z = fmaf(xv.z, qv.z, acc[q].z);
            acc[q].w = fmaf(xv.w, qv.w, acc[q].w);
          }
        }
      }
#pragma unroll
      for (int q = 0; q < QB; ++q)
        inner[q] = (acc[q].x + acc[q].y) + (acc[q].z + acc[q].w);
    }
    float sqm = sqb[b * N + m];
#pragma unroll
    for (int q = 0; q < QB; ++q) {
      float t = sqq[q] - 2.f * inner[q];
      t = t + sqm;
      dist[q][m] = -t;
    }
  }
  __syncthreads();

  // ---- wave-level selection: wave owns query q = wave; dist in registers ----
  {
    const int q = wave;
    const int nq = n0 + q;
    float v[32];
#pragma unroll
    for (int i = 0; i < 32; ++i) v[i] = dist[q][64 * i + lane];   // pipelined burst

    float lv = NEG_INF;
    int lm = 0;
#pragma unroll
    for (int i = 0; i < 32; ++i) {
      int m = 64 * i + lane;
      if (v[i] > lv) { lv = v[i]; lm = m; }   // ascending m: strict > keeps min index
    }
#pragma unroll 1
    for (int sel = 0; sel <= K; ++sel) {
      float bv = lv;
      int bm = lm;
#pragma unroll
      for (int s = 1; s < 64; s <<= 1) {
        float ov = __shfl_xor(bv, s);
        int om = __shfl_xor(bm, s);
        if (ov > bv || (ov == bv && om < bm)) { bv = ov; bm = om; }
      }
      if (sel > 0 && lane == 0)
        idxout[((size_t)(b * N) + nq) * K + (sel - 1)] = bm;
      // invalidate winner in registers (bm is wave-uniform; matches one lane)
#pragma unroll
      for (int i = 0; i < 32; ++i)
        if (64 * i + lane == bm) v[i] = NEG_INF;
      // winner lane recomputes its local argmax (exec-masked for others)
      if ((bm & 63) == lane) {
        lv = NEG_INF; lm = 0;
#pragma unroll
        for (int i = 0; i < 32; ++i) {
          int m = 64 * i + lane;
          if (v[i] > lv) { lv = v[i]; lm = m; }
        }
      }
    }
  }
}

// ---------------- build [W2 ; W1-W2] from edge weight (O, 2C), fp32 ---------
__global__ void wcomb_build(const float* __restrict__ w, float* __restrict__ wc, int O, int C) {
  int i = blockIdx.x * 256 + threadIdx.x;
  if (i >= O * C) return;
  int o = i / C, c = i % C;
  float w1 = w[o * 2 * C + c];
  float w2 = w[o * 2 * C + C + c];
  wc[(size_t)o * C + c] = w2;                 // u rows
  wc[(size_t)(O + o) * C + c] = w1 - w2;      // v rows
}

// ---------------- fp32 C = A(MxK,lda) * B(NcxK)^T ---------------------------
// LDS rows padded to 68 floats (272 B): keeps 16B alignment for ds_read_b128
// fragment reads (65-float rows were 260 B -> misaligned -> scalar ds_read).
__global__ __launch_bounds__(256) void gemm_abt(
    const float* __restrict__ A, int lda, const float* __restrict__ Bm,
    float* __restrict__ Cm, int ldc, int M, int Nc, int K) {
  __shared__ float As[16][68];
  __shared__ float Bs[16][68];
  const int tid = threadIdx.x;
  const int tx = tid & 15, ty = tid >> 4;
  const int n0 = blockIdx.x * 64;
  const int m0 = blockIdx.y * 64;
  float acc[4][4] = {};
  const int nkt = (K + 15) / 16;
  for (int kt = 0; kt < nkt; ++kt) {
    int k0 = kt * 16;
#pragma unroll
    for (int ph = 0; ph < 4; ++ph) {
      int idx = tid + 256 * ph;
      int k = idx & 15, mr = idx >> 4;
      float v = 0.f;
      if (k0 + k < K) v = A[(size_t)(m0 + mr) * lda + k0 + k];
      As[k][mr] = v;
    }
#pragma unroll
    for (int ph = 0; ph < 4; ++ph) {
      int idx = tid + 256 * ph;
      int k = idx & 15, nr = idx >> 4;
      float v = 0.f;
      if (k0 + k < K) v = Bm[(size_t)(n0 + nr) * K + k0 + k];
      Bs[k][nr] = v;
    }
    __syncthreads();
#pragma unroll
    for (int kk = 0; kk < 16; ++kk) {
      float av[4], bv[4];
#pragma unroll
      for (int r = 0; r < 4; ++r) av[r] = As[kk][4 * ty + r];
#pragma unroll
      for (int c = 0; c < 4; ++c) bv[c] = Bs[kk][4 * tx + c];
#pragma unroll
      for (int r = 0; r < 4; ++r)
#pragma unroll
        for (int c = 0; c < 4; ++c) acc[r][c] = fmaf(av[r], bv[c], acc[r][c]);
    }
    __syncthreads();
  }
#pragma unroll
  for (int r = 0; r < 4; ++r) {
    float4 v = make_float4(acc[r][0], acc[r][1], acc[r][2], acc[r][3]);
    *(float4*)&Cm[(size_t)(m0 + 4 * ty + r) * ldc + n0 + 4 * tx] = v;
  }
}

// ---------------- edge conv pass1: h = v_n + u_m; stats + max/min over k ----
__global__ void edge_pass1(const float* __restrict__ uv, const int* __restrict__ idx,
                           float* __restrict__ hmax, float* __restrict__ hmin,
                           float* __restrict__ part, int N, int O, int K) {
  int b = blockIdx.y, n = blockIdx.x, o = threadIdx.x;
  size_t row = (size_t)b * N + n;
  const int twoO = 2 * O;
  float vv = uv[row * twoO + O + o];
  const int* ib = idx + row * K;
  float mx = NEG_INF, mn = POS_INF, s = 0.f, ss = 0.f;
  for (int k = 0; k < K; ++k) {
    int m = ib[k];
    float h = vv + uv[((size_t)b * N + m) * twoO + o];
    mx = fmaxf(mx, h); mn = fminf(mn, h);
    s += h; ss = fmaf(h, h, ss);
  }
  hmax[row * O + o] = mx;
  hmin[row * O + o] = mn;
  __shared__ float2 red[256];
  red[o] = make_float2(s, ss);
  __syncthreads();
  int gsz = O >> 2;
  int lane = o & (gsz - 1);
  for (int off = gsz >> 1; off > 0; off >>= 1) {
    if (lane < off) { red[o].x += red[o + off].x; red[o].y += red[o + off].y; }
    __syncthreads();
  }
  if (lane == 0) {
    int g = o / gsz;
    part[row * 8 + g * 2] = red[o].x;
    part[row * 8 + g * 2 + 1] = red[o].y;
  }
}

__global__ void stats_reduce(const float* __restrict__ part, float* __restrict__ st, int N) {
  int g = blockIdx.x, b = blockIdx.y, tid = threadIdx.x;
  float s = 0.f, ss = 0.f;
  for (int n = tid; n < N; n += 256) {
    size_t base = ((size_t)b * N + n) * 8 + g * 2;
    s += part[base]; ss += part[base + 1];
  }
  __shared__ float2 red[256];
  red[tid] = make_float2(s, ss);
  __syncthreads();
  for (int off = 128; off > 0; off >>= 1) {
    if (tid < off) { red[tid].x += red[tid + off].x; red[tid].y += red[tid + off].y; }
    __syncthreads();
  }
  if (tid == 0) { st[(b * 4 + g) * 2] = red[0].x; st[(b * 4 + g) * 2 + 1] = red[0].y; }
}

__global__ void edge_pass2(const float* __restrict__ hmax, const float* __restrict__ hmin,
                           const float* __restrict__ st,
                           const float* __restrict__ gw, const float* __restrict__ gb,
                           float* __restrict__ outbase, int N, int O, int K, int coloff, int total) {
  int i = blockIdx.x * 256 + threadIdx.x;
  if (i >= total) return;
  int o = i % O;
  int n = (i / O) % N;
  int b = i / (O * N);
  int gsz = O >> 2;
  int g = o / gsz;
  float S = st[(b * 4 + g) * 2], SS = st[(b * 4 + g) * 2 + 1];
  float cnt = (float)N * (float)K * (float)gsz;
  float mean = S / cnt;
  float var = SS / cnt - mean * mean;
  float rs = rsqrtf(var + 1e-5f);
  float wf = gw[o], bf = gb[o];
  float Mv = (wf >= 0.f) ? hmax[i] : hmin[i];
  float val = (Mv - mean) * rs * wf + bf;
  outbase[((size_t)b * N + n) * 512 + coloff + o] = lk(val);
}

// ---------------- gn_seq stats: two-phase (round-5: 32-block version was
// 543 us at 1.4% occupancy / 0.6% VALUBusy -- pure parallelism starvation) ---
// Phase A: grid (4, 8, 16): block handles 256 channels x 128 rows.
__global__ void seq_part(const float* __restrict__ h, float4* __restrict__ pq, int N) {
  int b = blockIdx.y, chunk = blockIdx.z;
  int c = blockIdx.x * 256 + threadIdx.x;
  float mx = NEG_INF, mn = POS_INF, s = 0.f, ss = 0.f;
  int nbeg = chunk * 128;
#pragma unroll 1
  for (int n = nbeg; n < nbeg + 128; ++n) {
    float v = h[((size_t)b * N + n) * 1024 + c];
    mx = fmaxf(mx, v); mn = fminf(mn, v);
    s += v; ss = fmaf(v, v, ss);
  }
  pq[((size_t)(b * 16 + chunk)) * 1024 + c] = make_float4(mx, mn, s, ss);
}

// Phase B: grid (4, 8): combine 16 chunks, then per-group LDS reduction.
__global__ void seq_fin(const float4* __restrict__ pq, float* __restrict__ st16,
                        float* __restrict__ maxv, float* __restrict__ minv) {
  int b = blockIdx.y;
  int tid = threadIdx.x;
  int c = blockIdx.x * 256 + tid;
  float mx = NEG_INF, mn = POS_INF, s = 0.f, ss = 0.f;
#pragma unroll
  for (int ch = 0; ch < 16; ++ch) {
    float4 p = pq[((size_t)(b * 16 + ch)) * 1024 + c];
    mx = fmaxf(mx, p.x); mn = fminf(mn, p.y);
    s += p.z; ss += p.w;
  }
  maxv[b * 1024 + c] = mx;
  minv[b * 1024 + c] = mn;
  __shared__ float2 red[256];
  red[tid] = make_float2(s, ss);
  __syncthreads();
  int lane = tid & 63;
  for (int off = 32; off > 0; off >>= 1) {
    if (lane < off) { red[tid].x += red[tid + off].x; red[tid].y += red[tid + off].y; }
    __syncthreads();
  }
  if (lane == 0) {
    int g = c >> 6;
    st16[(b * 16 + g) * 2] = red[tid].x;
    st16[(b * 16 + g) * 2 + 1] = red[tid].y;
  }
}

__global__ void seq_apply(const float* __restrict__ st16, const float* __restrict__ maxv,
                          const float* __restrict__ minv, const float* __restrict__ gw,
                          const float* __restrict__ gb, float* __restrict__ g, int N) {
  int i = blockIdx.x * 256 + threadIdx.x;
  if (i >= 8 * 1024) return;
  int b = i >> 10, c = i & 1023;
  int grp = c >> 6;
  float S = st16[(b * 16 + grp) * 2], SS = st16[(b * 16 + grp) * 2 + 1];
  float cnt = (float)N * 64.f;
  float mean = S / cnt;
  float var = SS / cnt - mean * mean;
  float rs = rsqrtf(var + 1e-5f);
  float wf = gw[c], bf = gb[c];
  float Mv = (wf >= 0.f) ? maxv[i] : minv[i];
  g[i] = lk((Mv - mean) * rs * wf + bf);
}

// ---------------- small MLP head ----------------
__global__ void fc_kernel(const float* __restrict__ in, const float* __restrict__ w,
                          const float* __restrict__ bias, float* __restrict__ z,
                          int Cin, int Cout) {
  int b = blockIdx.y;
  int o = blockIdx.x * 64 + threadIdx.x;
  if (o >= Cout) return;
  const float* ir = in + (size_t)b * Cin;
  const float* wr = w + (size_t)o * Cin;
  float acc = 0.f;
  for (int c = 0; c < Cin; ++c) acc = fmaf(ir[c], wr[c], acc);
  z[b * Cout + o] = acc + bias[o];
}

__global__ void ln_leaky(const float* __restrict__ z, const float* __restrict__ w,
                         const float* __restrict__ bias, float* __restrict__ out, int Cn) {
  int b = blockIdx.x, tid = threadIdx.x;
  const float* zr = z + (size_t)b * Cn;
  float s = 0.f, ss = 0.f;
  for (int o = tid; o < Cn; o += 256) { float v = zr[o]; s += v; ss = fmaf(v, v, ss); }
  __shared__ float2 red[256];
  red[tid] = make_float2(s, ss);
  __syncthreads();
  for (int off = 128; off > 0; off >>= 1) {
    if (tid < off) { red[tid].x += red[tid + off].x; red[tid].y += red[tid + off].y; }
    __syncthreads();
  }
  float mean = red[0].x / Cn;
  float var = red[0].y / Cn - mean * mean;
  float rs = rsqrtf(var + 1e-5f);
  for (int o = tid; o < Cn; o += 256) {
    float v = (zr[o] - mean) * rs * w[o] + bias[o];
    out[b * Cn + o] = lk(v);
  }
}

__global__ void final_fc(const float* __restrict__ in, const float* __restrict__ w,
                         const float* __restrict__ bias, void* __restrict__ out,
                         const int* __restrict__ flag) {
  int t = threadIdx.x;
  if (t >= 16) return;
  int b = t >> 1, j = t & 1;
  float acc = 0.f;
  for (int c = 0; c < 64; ++c) acc = fmaf(in[b * 64 + c], w[j * 64 + c], acc);
  acc += bias[j];
  if (*flag) ((__hip_bfloat16*)out)[t] = __float2bfloat16(acc);
  else       ((float*)out)[t] = acc;
}

// ---------------- host-side dispatch helpers -----------------------
static void launch_sq(int C, const float* xin, int ldx, float* sqb, int BN, hipStream_t s) {
  dim3 g((BN + 255) / 256);
  if (C == 3)       sq_kernel<3><<<g, 256, 0, s>>>(xin, ldx, sqb, BN);
  else if (C == 64) sq_kernel<64><<<g, 256, 0, s>>>(xin, ldx, sqb, BN);
  else              sq_kernel<128><<<g, 256, 0, s>>>(xin, ldx, sqb, BN);
}
static void launch_knn(int C, const float* xin, int ldx, const float* sqb, int* idx,
                       int B, int N, int K, hipStream_t s) {
  dim3 g(N / 4, B);
  if (C == 3)       knn_kernel<3><<<g, 256, 0, s>>>(xin, ldx, sqb, idx, B, N, K);
  else if (C == 64) knn_kernel<64><<<g, 256, 0, s>>>(xin, ldx, sqb, idx, B, N, K);
  else              knn_kernel<128><<<g, 256, 0, s>>>(xin, ldx, sqb, idx, B, N, K);
}

extern "C" void kernel_launch(void* const* d_in, const int* in_sizes, int n_in,
                              void* d_out, int out_size, void* d_ws, size_t ws_size,
                              hipStream_t stream) {
  (void)out_size; (void)ws_size;
  const int B = 8, N = 2048, KNN = 20;
  const int BN = B * N;

  float* base = (float*)d_ws;
  size_t off = 0;
  auto alloc = [&](size_t nf) { float* p = base + off; off += nf; return p; };

  int*   FLAG  = (int*)alloc(16);
  float* XF    = alloc((size_t)BN * 3);
  float* HCAT  = alloc((size_t)BN * 512);
  float* BIG   = alloc((size_t)BN * 1024);   // UV | HMAX | HMIN during edge phase; H1024 after
  float* UV    = BIG;
  float* HMAX  = BIG + (size_t)BN * 512;
  float* HMIN  = BIG + (size_t)BN * 768;
  float* H1024 = BIG;
  float* SQB   = alloc(BN);
  float* WCOMB = alloc((size_t)512 * 128);
  float* PART  = alloc((size_t)BN * 8);
  float* ST4   = alloc(64);
  float* ST16  = alloc(512);
  float* PQST  = alloc((size_t)8 * 16 * 1024 * 4);   // seq_part float4 partials
  float* MAXV  = alloc(8 * 1024);
  float* MINV  = alloc(8 * 1024);
  float* GVEC  = alloc(8 * 1024);
  float* Z1 = alloc(8 * 512); float* A1v = alloc(8 * 512);
  float* Z2 = alloc(8 * 256); float* A2v = alloc(8 * 256);
  float* Z3 = alloc(8 * 64);  float* A3v = alloc(8 * 64);
  int*   IDX = (int*)alloc((size_t)BN * KNN);

  // converted fp32 weights
  ConvTable ct;
  float* conv_dst[30];
  for (int i = 0; i < 30; ++i) {
    int n = in_sizes[i];
    conv_dst[i] = alloc((size_t)((n + 15) & ~15));
    ct.src[i] = d_in[i];
    ct.dst[i] = conv_dst[i];
    ct.n[i] = n;
  }
  ct.dst[0] = XF; ct.n[0] = BN * 3;   // x goes straight to XF

  const float* W_[4]  = {conv_dst[1], conv_dst[4], conv_dst[7], conv_dst[10]};
  const float* GW_[4] = {conv_dst[2], conv_dst[5], conv_dst[8], conv_dst[11]};
  const float* GB_[4] = {conv_dst[3], conv_dst[6], conv_dst[9], conv_dst[12]};
  const float* WM = conv_dst[13];
  const float* GMW = conv_dst[14], *GMB = conv_dst[15];
  const float* FC1W = conv_dst[16], *FC1B = conv_dst[17], *LN1W = conv_dst[18], *LN1B = conv_dst[19];
  const float* FC2W = conv_dst[20], *FC2B = conv_dst[21], *LN2W = conv_dst[22], *LN2B = conv_dst[23];
  const float* FC3W = conv_dst[24], *FC3B = conv_dst[25], *LN3W = conv_dst[26], *LN3B = conv_dst[27];
  const float* FC4W = conv_dst[28], *FC4B = conv_dst[29];

  detect_dtype<<<dim3(1), 64, 0, stream>>>((const unsigned short*)d_in[0], FLAG);
  conv_all<<<dim3(2048, 30), 256, 0, stream>>>(ct, FLAG);

  const int Cs[4]     = {3, 64, 64, 128};
  const int Os[4]     = {64, 64, 128, 256};
  const int incol[4]  = {0, 0, 64, 128};
  const int outcol[4] = {0, 64, 128, 256};

  for (int l = 0; l < 4; ++l) {
    const int C = Cs[l], O = Os[l], twoO = 2 * O;
    const float* xin = (l == 0) ? XF : (HCAT + incol[l]);
    const int ldx = (l == 0) ? 3 : 512;

    launch_sq(C, xin, ldx, SQB, BN, stream);
    launch_knn(C, xin, ldx, SQB, IDX, B, N, KNN, stream);
    wcomb_build<<<dim3((O * C + 255) / 256), 256, 0, stream>>>(W_[l], WCOMB, O, C);
    gemm_abt<<<dim3(twoO / 64, BN / 64), 256, 0, stream>>>(xin, ldx, WCOMB, UV, twoO, BN, twoO, C);
    edge_pass1<<<dim3(N, B), O, 0, stream>>>(UV, IDX, HMAX, HMIN, PART, N, O, KNN);
    stats_reduce<<<dim3(4, B), 256, 0, stream>>>(PART, ST4, N);
    int tot = BN * O;
    edge_pass2<<<dim3((tot + 255) / 256), 256, 0, stream>>>(HMAX, HMIN, ST4, GW_[l], GB_[l],
                                                            HCAT, N, O, KNN, outcol[l], tot);
  }

  gemm_abt<<<dim3(1024 / 64, BN / 64), 256, 0, stream>>>(HCAT, 512, WM, H1024, 1024, BN, 1024, 512);
  seq_part<<<dim3(4, 8, 16), 256, 0, stream>>>(H1024, (float4*)PQST, N);
  seq_fin<<<dim3(4, 8), 256, 0, stream>>>((const float4*)PQST, ST16, MAXV, MINV);
  seq_apply<<<dim3(32), 256, 0, stream>>>(ST16, MAXV, MINV, GMW, GMB, GVEC, N);

  fc_kernel<<<dim3(8, 8), 64, 0, stream>>>(GVEC, FC1W, FC1B, Z1, 1024, 512);
  ln_leaky<<<dim3(8), 256, 0, stream>>>(Z1, LN1W, LN1B, A1v, 512);
  fc_kernel<<<dim3(4, 8), 64, 0, stream>>>(A1v, FC2W, FC2B, Z2, 512, 256);
  ln_leaky<<<dim3(8), 256, 0, stream>>>(Z2, LN2W, LN2B, A2v, 256);
  fc_kernel<<<dim3(1, 8), 64, 0, stream>>>(A2v, FC3W, FC3B, Z3, 256, 64);
  ln_leaky<<<dim3(8), 256, 0, stream>>>(Z3, LN3W, LN3B, A3v, 64);
  final_fc<<<dim3(1), 64, 0, stream>>>(A3v, FC4W, FC4B, d_out, FLAG);
}